// Round 1
// baseline (626.444 us; speedup 1.0000x reference)
//
#include <hip/hip_runtime.h>
#include <math.h>

#define DIM 512
#define HEADS 8
#define HD 64
#define ROWS_TOTAL 8192   // 4 * 2048
#define SEQ 2048

__device__ __forceinline__ float elu1(float x) {
    // elu(x) + 1
    return x > 0.f ? x + 1.f : __expf(x);
}

// ---------------- LayerNorm: one wave (64 lanes) per 512-wide row ----------
__global__ __launch_bounds__(256) void ln_kernel(const float* __restrict__ x,
                                                 const float* __restrict__ g,
                                                 const float* __restrict__ b,
                                                 float* __restrict__ out)
{
    int row  = blockIdx.x * 4 + (threadIdx.x >> 6);
    int lane = threadIdx.x & 63;
    const float* xr = x + (size_t)row * DIM + lane * 8;
    float4 v1 = *(const float4*)xr;
    float4 v2 = *(const float4*)(xr + 4);
    float s  = v1.x + v1.y + v1.z + v1.w + v2.x + v2.y + v2.z + v2.w;
    float sq = v1.x*v1.x + v1.y*v1.y + v1.z*v1.z + v1.w*v1.w
             + v2.x*v2.x + v2.y*v2.y + v2.z*v2.z + v2.w*v2.w;
#pragma unroll
    for (int off = 32; off > 0; off >>= 1) {
        s  += __shfl_xor(s,  off, 64);
        sq += __shfl_xor(sq, off, 64);
    }
    float mean = s * (1.f / DIM);
    float var  = sq * (1.f / DIM) - mean * mean;
    float rstd = rsqrtf(var + 1e-5f);
    int c = lane * 8;
    float4 ga = *(const float4*)(g + c);
    float4 gb = *(const float4*)(g + c + 4);
    float4 ba = *(const float4*)(b + c);
    float4 bb = *(const float4*)(b + c + 4);
    float4 o1, o2;
    o1.x = (v1.x - mean) * rstd * ga.x + ba.x;
    o1.y = (v1.y - mean) * rstd * ga.y + ba.y;
    o1.z = (v1.z - mean) * rstd * ga.z + ba.z;
    o1.w = (v1.w - mean) * rstd * ga.w + ba.w;
    o2.x = (v2.x - mean) * rstd * gb.x + bb.x;
    o2.y = (v2.y - mean) * rstd * gb.y + bb.y;
    o2.z = (v2.z - mean) * rstd * gb.z + bb.z;
    o2.w = (v2.w - mean) * rstd * gb.w + bb.w;
    float* op = out + (size_t)row * DIM + c;
    *(float4*)op       = o1;
    *(float4*)(op + 4) = o2;
}

// ---------------- fp32 tiled GEMM: C[M,N] = A[M,K] @ W[K,N] + bias --------
// epi: 0 = none, 1 = elu(v*scale)+1 (q-proj), 2 = elu(v)+1 (k-proj), 3 = relu
// resid (optional, M x N) added after activation.
__global__ __launch_bounds__(256) void gemm_kernel(
    const float* __restrict__ A, const float* __restrict__ W,
    const float* __restrict__ bias, const float* __restrict__ resid,
    float* __restrict__ C, int M, int K, int N, int epi, float scale)
{
    __shared__ float As[64][17];
    __shared__ float Ws[16][68];
    int tid = threadIdx.x;
    int tx = tid & 15, ty = tid >> 4;
    int m0 = blockIdx.y * 64, n0 = blockIdx.x * 64;
    int lr = tid >> 2;          // 0..63 A-row
    int lk = (tid & 3) * 4;     // 0,4,8,12 A-col
    int wk = tid >> 4;          // 0..15 W-row
    int wn = (tid & 15) * 4;    // 0..60 W-col
    float acc[4][4] = {};
    for (int k0 = 0; k0 < K; k0 += 16) {
        float4 av = *(const float4*)(A + (size_t)(m0 + lr) * K + k0 + lk);
        As[lr][lk + 0] = av.x; As[lr][lk + 1] = av.y;
        As[lr][lk + 2] = av.z; As[lr][lk + 3] = av.w;
        float4 wv = *(const float4*)(W + (size_t)(k0 + wk) * N + n0 + wn);
        Ws[wk][wn + 0] = wv.x; Ws[wk][wn + 1] = wv.y;
        Ws[wk][wn + 2] = wv.z; Ws[wk][wn + 3] = wv.w;
        __syncthreads();
#pragma unroll
        for (int kk = 0; kk < 16; ++kk) {
            float a[4], w[4];
#pragma unroll
            for (int i = 0; i < 4; ++i) a[i] = As[ty * 4 + i][kk];
#pragma unroll
            for (int j = 0; j < 4; ++j) w[j] = Ws[kk][tx * 4 + j];
#pragma unroll
            for (int i = 0; i < 4; ++i)
#pragma unroll
                for (int j = 0; j < 4; ++j)
                    acc[i][j] += a[i] * w[j];
        }
        __syncthreads();
    }
#pragma unroll
    for (int i = 0; i < 4; ++i) {
        int m = m0 + ty * 4 + i;
#pragma unroll
        for (int j = 0; j < 4; ++j) {
            int n = n0 + tx * 4 + j;
            float v = acc[i][j] + bias[n];
            if (epi == 1)      v = elu1(v * scale);
            else if (epi == 2) v = elu1(v);
            else if (epi == 3) v = fmaxf(v, 0.f);
            if (resid) v += resid[(size_t)m * N + n];
            C[(size_t)m * N + n] = v;
        }
    }
}

// ---------------- per-head KV = K^T V (64x64) + ksum, N-sliced + atomics ---
#define KV_SLICES 16
__global__ __launch_bounds__(256) void kv_kernel(
    const float* __restrict__ k, const float* __restrict__ v,
    float* __restrict__ kv, float* __restrict__ ksum)
{
    __shared__ float Ks[16][68];
    __shared__ float Vs[16][68];
    int bh = blockIdx.x;           // 0..31
    int b = bh >> 3, h = bh & 7;
    int tid = threadIdx.x;
    int rbase = b * SEQ + blockIdx.y * (SEQ / KV_SLICES);
    int lr = tid >> 4;             // 0..15
    int lc = (tid & 15) * 4;       // 0..60
    int e  = tid & 63;
    int d0 = (tid >> 6) * 16;
    float acc[16] = {};
    float ks_acc = 0.f;
    for (int c = 0; c < SEQ / KV_SLICES; c += 16) {
        const float* kp = k + (size_t)(rbase + c + lr) * DIM + h * HD + lc;
        float4 k4 = *(const float4*)kp;
        Ks[lr][lc + 0] = k4.x; Ks[lr][lc + 1] = k4.y;
        Ks[lr][lc + 2] = k4.z; Ks[lr][lc + 3] = k4.w;
        const float* vp = v + (size_t)(rbase + c + lr) * DIM + h * HD + lc;
        float4 v4 = *(const float4*)vp;
        Vs[lr][lc + 0] = v4.x; Vs[lr][lc + 1] = v4.y;
        Vs[lr][lc + 2] = v4.z; Vs[lr][lc + 3] = v4.w;
        __syncthreads();
#pragma unroll
        for (int nn = 0; nn < 16; ++nn) {
            float vv = Vs[nn][e];
#pragma unroll
            for (int i = 0; i < 16; ++i)
                acc[i] += Ks[nn][d0 + i] * vv;
            if (d0 == 0) ks_acc += Ks[nn][e];
        }
        __syncthreads();
    }
    float* kvp = kv + (size_t)bh * (HD * HD);
#pragma unroll
    for (int i = 0; i < 16; ++i)
        atomicAdd(kvp + (d0 + i) * HD + e, acc[i]);
    if (d0 == 0) atomicAdd(ksum + bh * HD + e, ks_acc);
}

// ---------------- attn out: out[n,:] = q[n,:] @ KV / (q[n,:].ksum + 1e-5) --
__global__ __launch_bounds__(256) void attn_kernel(
    const float* __restrict__ q, const float* __restrict__ kv,
    const float* __restrict__ ksum, float* __restrict__ out)
{
    __shared__ float KVs[HD * HD];
    __shared__ float qs[4][HD];
    __shared__ float kss[HD];
    int bh = blockIdx.x;
    int b = bh >> 3, h = bh & 7;
    int tid = threadIdx.x;
    int e = tid & 63, r = tid >> 6;
    int n0 = blockIdx.y * 4;
    const float* kvp = kv + (size_t)bh * (HD * HD);
#pragma unroll
    for (int i = 0; i < 4; ++i)
        *(float4*)&KVs[i * 1024 + tid * 4] = *(const float4*)(kvp + i * 1024 + tid * 4);
    int gr = b * SEQ + n0 + r;
    qs[r][e] = q[(size_t)gr * DIM + h * HD + e];
    if (tid < HD) kss[tid] = ksum[bh * HD + tid];
    __syncthreads();
    float denom = 1e-5f;
    float o = 0.f;
#pragma unroll
    for (int d = 0; d < HD; ++d) {
        float qd = qs[r][d];
        denom += qd * kss[d];
        o += qd * KVs[d * HD + e];
    }
    out[(size_t)gr * DIM + h * HD + e] = o / denom;
}

extern "C" void kernel_launch(void* const* d_in, const int* in_sizes, int n_in,
                              void* d_out, int out_size, void* d_ws, size_t ws_size,
                              hipStream_t stream)
{
    const float* x   = (const float*)d_in[0];
    const float* Wq  = (const float*)d_in[1];
    const float* bq  = (const float*)d_in[2];
    const float* Wk  = (const float*)d_in[3];
    const float* bk  = (const float*)d_in[4];
    const float* Wv  = (const float*)d_in[5];
    const float* bv  = (const float*)d_in[6];
    const float* Wo  = (const float*)d_in[7];
    const float* bo  = (const float*)d_in[8];
    const float* W1  = (const float*)d_in[9];
    const float* b1  = (const float*)d_in[10];
    const float* W2  = (const float*)d_in[11];
    const float* b2  = (const float*)d_in[12];
    const float* g1  = (const float*)d_in[13];
    const float* be1 = (const float*)d_in[14];
    const float* g2  = (const float*)d_in[15];
    const float* be2 = (const float*)d_in[16];

    float* ws = (float*)d_ws;
    float* A  = ws;                       // 4M floats: xn, later h (LN2 out)
    float* Q  = ws + (size_t)4  * 1024 * 1024;  // 4M floats
    float* Kb = ws + (size_t)8  * 1024 * 1024;  // 4M floats: k, later attn_out
    float* V  = ws + (size_t)12 * 1024 * 1024;  // 4M floats: v, later y
    float* F1 = Q;                        // 8M floats, spans Q+Kb (both free then)
    float* KV = ws + (size_t)16 * 1024 * 1024;  // 32 * 4096
    float* KS = KV + 32 * HD * HD;              // 32 * 64

    float* out = (float*)d_out;

    dim3 blk(256);
    dim3 g512(8, 128);    // N=512 tiles x M=8192 tiles
    dim3 g1024(16, 128);  // N=1024

    // 1. xn = LN1(x)
    ln_kernel<<<2048, blk, 0, stream>>>(x, g1, be1, A);
    // 2-4. q/k/v projections with fused activations
    gemm_kernel<<<g512, blk, 0, stream>>>(A, Wq, bq, nullptr, Q,  ROWS_TOTAL, 512, 512, 1, 0.125f);
    gemm_kernel<<<g512, blk, 0, stream>>>(A, Wk, bk, nullptr, Kb, ROWS_TOTAL, 512, 512, 2, 1.f);
    gemm_kernel<<<g512, blk, 0, stream>>>(A, Wv, bv, nullptr, V,  ROWS_TOTAL, 512, 512, 0, 1.f);
    // 5. KV = K^T V, ksum (per head)
    hipMemsetAsync(KV, 0, (size_t)(32 * HD * HD + 32 * HD) * sizeof(float), stream);
    kv_kernel<<<dim3(32, KV_SLICES), blk, 0, stream>>>(Kb, V, KV, KS);
    // 6. attn = q @ KV / denom  (overwrites k-buffer)
    attn_kernel<<<dim3(32, SEQ / 4), blk, 0, stream>>>(Q, KV, KS, Kb);
    // 7. y = x + attn @ Wo + bo  (into V's buffer)
    gemm_kernel<<<g512, blk, 0, stream>>>(Kb, Wo, bo, x, V, ROWS_TOTAL, 512, 512, 0, 1.f);
    // 8. h = LN2(y)
    ln_kernel<<<2048, blk, 0, stream>>>(V, g2, be2, A);
    // 9. f1 = relu(h @ W1 + b1)
    gemm_kernel<<<g1024, blk, 0, stream>>>(A, W1, b1, nullptr, F1, ROWS_TOTAL, 512, 1024, 3, 1.f);
    // 10. out = y + f1 @ W2 + b2
    gemm_kernel<<<g512, blk, 0, stream>>>(F1, W2, b2, V, out, ROWS_TOTAL, 1024, 512, 0, 1.f);
}

// Round 2
// 222.374 us; speedup vs baseline: 2.8171x; 2.8171x over previous
//
#include <hip/hip_runtime.h>
#include <hip/hip_bf16.h>
#include <math.h>

#define DIM 512
#define HEADS 8
#define HD 64
#define ROWS_TOTAL 8192   // 4 * 2048
#define SEQ 2048

typedef __hip_bfloat16 bf16;
typedef __bf16 bf16x8 __attribute__((ext_vector_type(8)));
typedef float f32x4 __attribute__((ext_vector_type(4)));

__device__ __forceinline__ float elu1(float x) {
    return x > 0.f ? x + 1.f : __expf(x);
}

__device__ __forceinline__ void gl16(const void* g, void* l) {
    __builtin_amdgcn_global_load_lds(
        (const __attribute__((address_space(1))) void*)g,
        (__attribute__((address_space(3))) void*)l, 16, 0, 0);
}

// ---------------- LayerNorm: one wave per 512-wide row, bf16 output -------
__global__ __launch_bounds__(256) void ln_kernel(const float* __restrict__ x,
                                                 const float* __restrict__ g,
                                                 const float* __restrict__ b,
                                                 bf16* __restrict__ out)
{
    int row  = blockIdx.x * 4 + (threadIdx.x >> 6);
    int lane = threadIdx.x & 63;
    const float* xr = x + (size_t)row * DIM + lane * 8;
    float4 v1 = *(const float4*)xr;
    float4 v2 = *(const float4*)(xr + 4);
    float s  = v1.x + v1.y + v1.z + v1.w + v2.x + v2.y + v2.z + v2.w;
    float sq = v1.x*v1.x + v1.y*v1.y + v1.z*v1.z + v1.w*v1.w
             + v2.x*v2.x + v2.y*v2.y + v2.z*v2.z + v2.w*v2.w;
#pragma unroll
    for (int off = 32; off > 0; off >>= 1) {
        s  += __shfl_xor(s,  off, 64);
        sq += __shfl_xor(sq, off, 64);
    }
    float mean = s * (1.f / DIM);
    float var  = sq * (1.f / DIM) - mean * mean;
    float rstd = rsqrtf(var + 1e-5f);
    int c = lane * 8;
    float4 ga = *(const float4*)(g + c);
    float4 gb = *(const float4*)(g + c + 4);
    float4 ba = *(const float4*)(b + c);
    float4 bb = *(const float4*)(b + c + 4);
    bf16 ob[8];
    ob[0] = __float2bfloat16((v1.x - mean) * rstd * ga.x + ba.x);
    ob[1] = __float2bfloat16((v1.y - mean) * rstd * ga.y + ba.y);
    ob[2] = __float2bfloat16((v1.z - mean) * rstd * ga.z + ba.z);
    ob[3] = __float2bfloat16((v1.w - mean) * rstd * ga.w + ba.w);
    ob[4] = __float2bfloat16((v2.x - mean) * rstd * gb.x + bb.x);
    ob[5] = __float2bfloat16((v2.y - mean) * rstd * gb.y + bb.y);
    ob[6] = __float2bfloat16((v2.z - mean) * rstd * gb.z + bb.z);
    ob[7] = __float2bfloat16((v2.w - mean) * rstd * gb.w + bb.w);
    *(uint4*)(out + (size_t)row * DIM + c) = *(uint4*)ob;
}

// ---------------- transpose+convert all 6 weights: W[K][N] -> Wt[N][K] bf16
__global__ __launch_bounds__(256) void wtall_kernel(
    const float* __restrict__ Wq, const float* __restrict__ Wk,
    const float* __restrict__ Wv, const float* __restrict__ Wo,
    const float* __restrict__ W1, const float* __restrict__ W2,
    bf16* WqT, bf16* WkT, bf16* WvT, bf16* WoT, bf16* W1T, bf16* W2T)
{
    __shared__ float t[32][33];
    int bx = blockIdx.x;
    const float* W; bf16* T; int K, N, tk, tn;
    if (bx < 1024) {
        int m = bx >> 8, tix = bx & 255;
        const float* ws_[4] = {Wq, Wk, Wv, Wo};
        bf16* ts_[4] = {WqT, WkT, WvT, WoT};
        W = ws_[m]; T = ts_[m]; K = 512; N = 512; tn = tix & 15; tk = tix >> 4;
    } else if (bx < 1536) {
        int tix = bx - 1024; W = W1; T = W1T; K = 512; N = 1024; tn = tix & 31; tk = tix >> 5;
    } else {
        int tix = bx - 1536; W = W2; T = W2T; K = 1024; N = 512; tn = tix & 15; tk = tix >> 4;
    }
    int n0 = tn * 32, k0 = tk * 32;
    int tx = threadIdx.x & 31, ty = threadIdx.x >> 5;   // ty 0..7
#pragma unroll
    for (int i = 0; i < 32; i += 8)
        t[ty + i][tx] = W[(size_t)(k0 + ty + i) * N + n0 + tx];
    __syncthreads();
#pragma unroll
    for (int i = 0; i < 32; i += 8)
        T[(size_t)(n0 + ty + i) * K + k0 + tx] = __float2bfloat16(t[tx][ty + i]);
}

// ---------------- bf16 MFMA GEMM: C[M,N] = A[M,K] @ Bt[N,K]^T + bias ------
// EPI: 0 none, 1 elu1(v*scale), 2 elu1(v), 3 relu.  resid optional fp32.
template<int EPI, bool OUTBF>
__global__ __launch_bounds__(256) void mfma_gemm(
    const bf16* __restrict__ A, const bf16* __restrict__ Bt,
    const float* __restrict__ bias, const float* __restrict__ resid,
    void* __restrict__ Cout, int M, int N, int K, float scale)
{
    __shared__ bf16 As[128 * 32];   // [row][k] row-major, 8 KB
    __shared__ bf16 Bs[64 * 32];    // [n][k]  row-major, 4 KB
    int tid = threadIdx.x;
    int lane = tid & 63, wid = tid >> 6;
    int wr = wid >> 1, wc = wid & 1;           // wave -> (2x2) of 64x32 tiles
    int m0 = blockIdx.y * 128, n0 = blockIdx.x * 64;
    int r = lane >> 2, kc = (lane & 3) * 8;    // staging lane layout

    const bf16* ga0 = A  + (size_t)(m0 + wid * 32 +  r) * K + kc;
    const bf16* ga1 = ga0 + (size_t)16 * K;
    const bf16* gb  = Bt + (size_t)(n0 + wid * 16 +  r) * K + kc;
    bf16* la0 = &As[wid * 1024];
    bf16* la1 = &As[wid * 1024 + 512];
    bf16* lb  = &Bs[wid * 512];

    f32x4 acc[4][2] = {};
    int la = lane & 15, ka = lane >> 4;
    for (int k0 = 0; k0 < K; k0 += 32) {
        gl16(ga0 + k0, la0);
        gl16(ga1 + k0, la1);
        gl16(gb  + k0, lb);
        __syncthreads();
        const bf16x8* Av = (const bf16x8*)As;
        const bf16x8* Bv = (const bf16x8*)Bs;
        bf16x8 a[4], b[2];
#pragma unroll
        for (int m = 0; m < 4; ++m)
            a[m] = Av[(wr * 64 + m * 16 + la) * 4 + ka];
#pragma unroll
        for (int n = 0; n < 2; ++n)
            b[n] = Bv[(wc * 32 + n * 16 + la) * 4 + ka];
#pragma unroll
        for (int m = 0; m < 4; ++m)
#pragma unroll
            for (int n = 0; n < 2; ++n)
                acc[m][n] = __builtin_amdgcn_mfma_f32_16x16x32_bf16(a[m], b[n], acc[m][n], 0, 0, 0);
        __syncthreads();
    }

    int rg = (lane >> 4) * 4;
    float bv_[2];
#pragma unroll
    for (int n = 0; n < 2; ++n) bv_[n] = bias[n0 + wc * 32 + n * 16 + la];
#pragma unroll
    for (int m = 0; m < 4; ++m) {
        int gm = m0 + wr * 64 + m * 16 + rg;
#pragma unroll
        for (int n = 0; n < 2; ++n) {
            int gn = n0 + wc * 32 + n * 16 + la;
#pragma unroll
            for (int j = 0; j < 4; ++j) {
                float v = acc[m][n][j] + bv_[n];
                if (EPI == 1)      v = elu1(v * scale);
                else if (EPI == 2) v = elu1(v);
                else if (EPI == 3) v = fmaxf(v, 0.f);
                if (resid) v += resid[(size_t)(gm + j) * N + gn];
                if (OUTBF) ((bf16*)Cout)[(size_t)(gm + j) * N + gn] = __float2bfloat16(v);
                else       ((float*)Cout)[(size_t)(gm + j) * N + gn] = v;
            }
        }
    }
}

// ---------------- per-head KV = K^T V (64x64) + ksum, N-sliced + atomics ---
#define KV_SLICES 16
__global__ __launch_bounds__(256) void kv_kernel(
    const float* __restrict__ k, const float* __restrict__ v,
    float* __restrict__ kv, float* __restrict__ ksum)
{
    __shared__ float Ks[16][68];
    __shared__ float Vs[16][68];
    int bh = blockIdx.x;           // 0..31
    int b = bh >> 3, h = bh & 7;
    int tid = threadIdx.x;
    int rbase = b * SEQ + blockIdx.y * (SEQ / KV_SLICES);
    int lr = tid >> 4;
    int lc = (tid & 15) * 4;
    int e  = tid & 63;
    int d0 = (tid >> 6) * 16;
    float acc[16] = {};
    float ks_acc = 0.f;
    for (int c = 0; c < SEQ / KV_SLICES; c += 16) {
        const float* kp = k + (size_t)(rbase + c + lr) * DIM + h * HD + lc;
        float4 k4 = *(const float4*)kp;
        Ks[lr][lc + 0] = k4.x; Ks[lr][lc + 1] = k4.y;
        Ks[lr][lc + 2] = k4.z; Ks[lr][lc + 3] = k4.w;
        const float* vp = v + (size_t)(rbase + c + lr) * DIM + h * HD + lc;
        float4 v4 = *(const float4*)vp;
        Vs[lr][lc + 0] = v4.x; Vs[lr][lc + 1] = v4.y;
        Vs[lr][lc + 2] = v4.z; Vs[lr][lc + 3] = v4.w;
        __syncthreads();
#pragma unroll
        for (int nn = 0; nn < 16; ++nn) {
            float vv = Vs[nn][e];
#pragma unroll
            for (int i = 0; i < 16; ++i)
                acc[i] += Ks[nn][d0 + i] * vv;
            if (d0 == 0) ks_acc += Ks[nn][e];
        }
        __syncthreads();
    }
    float* kvp = kv + (size_t)bh * (HD * HD);
#pragma unroll
    for (int i = 0; i < 16; ++i)
        atomicAdd(kvp + (d0 + i) * HD + e, acc[i]);
    if (d0 == 0) atomicAdd(ksum + bh * HD + e, ks_acc);
}

// ---------------- attn out: out[n,:] = q[n,:] @ KV / (q[n,:].ksum + 1e-5) --
__global__ __launch_bounds__(256) void attn_kernel(
    const float* __restrict__ q, const float* __restrict__ kv,
    const float* __restrict__ ksum, bf16* __restrict__ out)
{
    __shared__ float KVs[HD * HD];
    __shared__ float qs[4][HD];
    __shared__ float kss[HD];
    int bh = blockIdx.x;
    int b = bh >> 3, h = bh & 7;
    int tid = threadIdx.x;
    int e = tid & 63, r = tid >> 6;
    int n0 = blockIdx.y * 4;
    const float* kvp = kv + (size_t)bh * (HD * HD);
#pragma unroll
    for (int i = 0; i < 4; ++i)
        *(float4*)&KVs[i * 1024 + tid * 4] = *(const float4*)(kvp + i * 1024 + tid * 4);
    int gr = b * SEQ + n0 + r;
    qs[r][e] = q[(size_t)gr * DIM + h * HD + e];
    if (tid < HD) kss[tid] = ksum[bh * HD + tid];
    __syncthreads();
    float denom = 1e-5f;
    float o = 0.f;
#pragma unroll
    for (int d = 0; d < HD; ++d) {
        float qd = qs[r][d];
        denom += qd * kss[d];
        o += qd * KVs[d * HD + e];
    }
    out[(size_t)gr * DIM + h * HD + e] = __float2bfloat16(o / denom);
}

extern "C" void kernel_launch(void* const* d_in, const int* in_sizes, int n_in,
                              void* d_out, int out_size, void* d_ws, size_t ws_size,
                              hipStream_t stream)
{
    const float* x   = (const float*)d_in[0];
    const float* Wq  = (const float*)d_in[1];
    const float* bq  = (const float*)d_in[2];
    const float* Wk  = (const float*)d_in[3];
    const float* bk  = (const float*)d_in[4];
    const float* Wv  = (const float*)d_in[5];
    const float* bv  = (const float*)d_in[6];
    const float* Wo  = (const float*)d_in[7];
    const float* bo  = (const float*)d_in[8];
    const float* W1  = (const float*)d_in[9];
    const float* b1  = (const float*)d_in[10];
    const float* W2  = (const float*)d_in[11];
    const float* b2  = (const float*)d_in[12];
    const float* g1  = (const float*)d_in[13];
    const float* be1 = (const float*)d_in[14];
    const float* g2  = (const float*)d_in[15];
    const float* be2 = (const float*)d_in[16];

    char* wsb = (char*)d_ws;
    const size_t MB = 1u << 20;
    float* Qf  = (float*)(wsb + 0 * MB);     // 16 MB; later F1 bf16 [8192,1024]
    float* Kf  = (float*)(wsb + 16 * MB);    // 16 MB; later y fp32
    float* Vf  = (float*)(wsb + 32 * MB);    // 16 MB; later h bf16
    bf16*  xn  = (bf16*)(wsb + 48 * MB);     // 8 MB;  later attn bf16
    bf16*  WqT = (bf16*)(wsb + 56 * MB);
    bf16*  WkT = WqT + 512 * 512;
    bf16*  WvT = WkT + 512 * 512;
    bf16*  WoT = WvT + 512 * 512;
    bf16*  W1T = WoT + 512 * 512;            // [1024][512]
    bf16*  W2T = W1T + 512 * 1024;           // [512][1024]
    float* KV  = (float*)(wsb + 62 * MB);    // 32 * 4096 floats
    float* KS  = KV + 32 * HD * HD;          // 32 * 64 floats
    bf16*  F1    = (bf16*)Qf;
    float* y     = Kf;
    bf16*  h     = (bf16*)Vf;
    bf16*  attnb = xn;

    float* out = (float*)d_out;
    dim3 blk(256);
    dim3 gp(512 / 64, ROWS_TOTAL / 128);   // N=512 GEMMs
    dim3 gm1(1024 / 64, ROWS_TOTAL / 128); // N=1024 GEMM

    // 0. transpose+convert all weights to bf16 [N][K]
    wtall_kernel<<<2048, blk, 0, stream>>>(Wq, Wk, Wv, Wo, W1, W2,
                                           WqT, WkT, WvT, WoT, W1T, W2T);
    // 1. xn = LN1(x) (bf16)
    ln_kernel<<<2048, blk, 0, stream>>>(x, g1, be1, xn);
    // 2-4. q/k/v projections (fp32 out, fused activations)
    mfma_gemm<1, false><<<gp, blk, 0, stream>>>(xn, WqT, bq, nullptr, Qf, ROWS_TOTAL, 512, 512, 0.125f);
    mfma_gemm<2, false><<<gp, blk, 0, stream>>>(xn, WkT, bk, nullptr, Kf, ROWS_TOTAL, 512, 512, 1.f);
    mfma_gemm<0, false><<<gp, blk, 0, stream>>>(xn, WvT, bv, nullptr, Vf, ROWS_TOTAL, 512, 512, 1.f);
    // 5. KV = K^T V, ksum (per head)
    hipMemsetAsync(KV, 0, (size_t)(32 * HD * HD + 32 * HD) * sizeof(float), stream);
    kv_kernel<<<dim3(32, KV_SLICES), blk, 0, stream>>>(Kf, Vf, KV, KS);
    // 6. attn = q @ KV / denom  (bf16, overwrites xn)
    attn_kernel<<<dim3(32, SEQ / 4), blk, 0, stream>>>(Qf, KV, KS, attnb);
    // 7. y = x + attn @ Wo + bo  (fp32, into Kf region)
    mfma_gemm<0, false><<<gp, blk, 0, stream>>>(attnb, WoT, bo, x, y, ROWS_TOTAL, 512, 512, 1.f);
    // 8. h = LN2(y) (bf16)
    ln_kernel<<<2048, blk, 0, stream>>>(y, g2, be2, h);
    // 9. f1 = relu(h @ W1 + b1) (bf16, into Qf region)
    mfma_gemm<3, true><<<gm1, blk, 0, stream>>>(h, W1T, b1, nullptr, F1, ROWS_TOTAL, 1024, 512, 1.f);
    // 10. out = y + f1 @ W2 + b2 (fp32)
    mfma_gemm<0, false><<<gp, blk, 0, stream>>>(F1, W2T, b2, y, out, ROWS_TOTAL, 512, 1024, 1.f);
}

// Round 3
// 184.154 us; speedup vs baseline: 3.4017x; 1.2075x over previous
//
#include <hip/hip_runtime.h>
#include <hip/hip_bf16.h>
#include <math.h>

#define DIM 512
#define HEADS 8
#define HD 64
#define ROWS_TOTAL 8192   // 4 * 2048
#define SEQ 2048

typedef __hip_bfloat16 bf16;
typedef __bf16 bf16x8 __attribute__((ext_vector_type(8)));
typedef float f32x4 __attribute__((ext_vector_type(4)));

__device__ __forceinline__ float elu1(float x) {
    return x > 0.f ? x + 1.f : __expf(x);
}
__device__ __forceinline__ float b2f(unsigned short u) {
    return __uint_as_float(((unsigned int)u) << 16);
}
__device__ __forceinline__ void gl16(const void* g, void* l) {
    __builtin_amdgcn_global_load_lds(
        (const __attribute__((address_space(1))) void*)g,
        (__attribute__((address_space(3))) void*)l, 16, 0, 0);
}

// ---------------- LayerNorm: one wave per 512-wide row, bf16 output -------
__global__ __launch_bounds__(256) void ln_kernel(const float* __restrict__ x,
                                                 const float* __restrict__ g,
                                                 const float* __restrict__ b,
                                                 bf16* __restrict__ out)
{
    int row  = blockIdx.x * 4 + (threadIdx.x >> 6);
    int lane = threadIdx.x & 63;
    const float* xr = x + (size_t)row * DIM + lane * 8;
    float4 v1 = *(const float4*)xr;
    float4 v2 = *(const float4*)(xr + 4);
    float s  = v1.x + v1.y + v1.z + v1.w + v2.x + v2.y + v2.z + v2.w;
    float sq = v1.x*v1.x + v1.y*v1.y + v1.z*v1.z + v1.w*v1.w
             + v2.x*v2.x + v2.y*v2.y + v2.z*v2.z + v2.w*v2.w;
#pragma unroll
    for (int off = 32; off > 0; off >>= 1) {
        s  += __shfl_xor(s,  off, 64);
        sq += __shfl_xor(sq, off, 64);
    }
    float mean = s * (1.f / DIM);
    float var  = sq * (1.f / DIM) - mean * mean;
    float rstd = rsqrtf(var + 1e-5f);
    int c = lane * 8;
    float4 ga = *(const float4*)(g + c);
    float4 gb = *(const float4*)(g + c + 4);
    float4 ba = *(const float4*)(b + c);
    float4 bb = *(const float4*)(b + c + 4);
    bf16 ob[8];
    ob[0] = __float2bfloat16((v1.x - mean) * rstd * ga.x + ba.x);
    ob[1] = __float2bfloat16((v1.y - mean) * rstd * ga.y + ba.y);
    ob[2] = __float2bfloat16((v1.z - mean) * rstd * ga.z + ba.z);
    ob[3] = __float2bfloat16((v1.w - mean) * rstd * ga.w + ba.w);
    ob[4] = __float2bfloat16((v2.x - mean) * rstd * gb.x + bb.x);
    ob[5] = __float2bfloat16((v2.y - mean) * rstd * gb.y + bb.y);
    ob[6] = __float2bfloat16((v2.z - mean) * rstd * gb.z + bb.z);
    ob[7] = __float2bfloat16((v2.w - mean) * rstd * gb.w + bb.w);
    *(uint4*)(out + (size_t)row * DIM + c) = *(uint4*)ob;
}

// ---------------- transpose+convert all 6 weights: W[K][N] -> Wt[N][K] bf16
__global__ __launch_bounds__(256) void wtall_kernel(
    const float* __restrict__ Wq, const float* __restrict__ Wk,
    const float* __restrict__ Wv, const float* __restrict__ Wo,
    const float* __restrict__ W1, const float* __restrict__ W2,
    bf16* WqT, bf16* WkT, bf16* WvT, bf16* WoT, bf16* W1T, bf16* W2T)
{
    __shared__ float t[32][33];
    int bx = blockIdx.x;
    const float* W; bf16* T; int K, N, tk, tn;
    if (bx < 1024) {
        int m = bx >> 8, tix = bx & 255;
        const float* ws_[4] = {Wq, Wk, Wv, Wo};
        bf16* ts_[4] = {WqT, WkT, WvT, WoT};
        W = ws_[m]; T = ts_[m]; K = 512; N = 512; tn = tix & 15; tk = tix >> 4;
    } else if (bx < 1536) {
        int tix = bx - 1024; W = W1; T = W1T; K = 512; N = 1024; tn = tix & 31; tk = tix >> 5;
    } else {
        int tix = bx - 1536; W = W2; T = W2T; K = 1024; N = 512; tn = tix & 15; tk = tix >> 4;
    }
    int n0 = tn * 32, k0 = tk * 32;
    int tx = threadIdx.x & 31, ty = threadIdx.x >> 5;   // ty 0..7
#pragma unroll
    for (int i = 0; i < 32; i += 8)
        t[ty + i][tx] = W[(size_t)(k0 + ty + i) * N + n0 + tx];
    __syncthreads();
#pragma unroll
    for (int i = 0; i < 32; i += 8)
        T[(size_t)(n0 + ty + i) * K + k0 + tx] = __float2bfloat16(t[tx][ty + i]);
}

// ---------------- 128x128 bf16 MFMA GEMM (m97 structure) -------------------
// EPI 0: fp32 out (+resid opt).  EPI 1: QKV-split bf16 out.  EPI 3: relu bf16.
template<int EPI>
__global__ __launch_bounds__(256) void mfma_gemm128(
    const bf16* __restrict__ A, const bf16* __restrict__ Bt,
    const float* __restrict__ b0, const float* __restrict__ b1,
    const float* __restrict__ b2, const float* __restrict__ resid,
    void* __restrict__ O0, void* __restrict__ O1, void* __restrict__ O2,
    int M, int N, int K, float scale)
{
    __shared__ __align__(16) bf16 As[128 * 32];
    __shared__ __align__(16) bf16 Bs[128 * 32];
    int tid = threadIdx.x;
    int lane = tid & 63, wid = tid >> 6;
    int wr = wid >> 1, wc = wid & 1;
    int m0 = blockIdx.y * 128, n0 = blockIdx.x * 128;
    int sr = tid >> 2;              // 0..63 staging row
    int sc = (tid & 3) * 8;         // staging col (bf16)
    const bf16* ga = A  + (size_t)(m0 + sr) * K + sc;
    const bf16* gb = Bt + (size_t)(n0 + sr) * K + sc;
    bf16* lA = &As[tid * 8];
    bf16* lB = &Bs[tid * 8];
    f32x4 acc[4][4] = {};
    int la = lane & 15, ka = lane >> 4;
    for (int k0 = 0; k0 < K; k0 += 32) {
        gl16(ga + k0, lA);
        gl16(ga + (size_t)64 * K + k0, lA + 2048);
        gl16(gb + k0, lB);
        gl16(gb + (size_t)64 * K + k0, lB + 2048);
        __syncthreads();
        const bf16x8* Av = (const bf16x8*)As;
        const bf16x8* Bv = (const bf16x8*)Bs;
        bf16x8 a[4], b[4];
#pragma unroll
        for (int m = 0; m < 4; ++m) a[m] = Av[(wr * 64 + m * 16 + la) * 4 + ka];
#pragma unroll
        for (int n = 0; n < 4; ++n) b[n] = Bv[(wc * 64 + n * 16 + la) * 4 + ka];
#pragma unroll
        for (int m = 0; m < 4; ++m)
#pragma unroll
            for (int n = 0; n < 4; ++n)
                acc[m][n] = __builtin_amdgcn_mfma_f32_16x16x32_bf16(a[m], b[n], acc[m][n], 0, 0, 0);
        __syncthreads();
    }

    int rg = (lane >> 4) * 4;
    if (EPI == 1) {
        // QKV split: bx 0-3 -> q(elu1(v*scale)), 4-7 -> k(elu1), 8-11 -> v(none)
        int bsel = blockIdx.x >> 2;
        bf16* Ob = (bf16*)(bsel == 0 ? O0 : (bsel == 1 ? O1 : O2));
        const float* bb = bsel == 0 ? b0 : (bsel == 1 ? b1 : b2);
        int nloc0 = (blockIdx.x & 3) * 128;
#pragma unroll
        for (int m = 0; m < 4; ++m) {
            int gm = m0 + wr * 64 + m * 16 + rg;
#pragma unroll
            for (int n = 0; n < 4; ++n) {
                int gnl = nloc0 + wc * 64 + n * 16 + la;
                float bv_ = bb[gnl];
#pragma unroll
                for (int j = 0; j < 4; ++j) {
                    float v = acc[m][n][j] + bv_;
                    if (bsel == 0)      v = elu1(v * scale);
                    else if (bsel == 1) v = elu1(v);
                    Ob[(size_t)(gm + j) * 512 + gnl] = __float2bfloat16(v);
                }
            }
        }
    } else {
#pragma unroll
        for (int m = 0; m < 4; ++m) {
            int gm = m0 + wr * 64 + m * 16 + rg;
#pragma unroll
            for (int n = 0; n < 4; ++n) {
                int gn = n0 + wc * 64 + n * 16 + la;
                float bv_ = b0[gn];
#pragma unroll
                for (int j = 0; j < 4; ++j) {
                    float v = acc[m][n][j] + bv_;
                    if (EPI == 3) v = fmaxf(v, 0.f);
                    if (resid) v += resid[(size_t)(gm + j) * N + gn];
                    if (EPI == 3) ((bf16*)O0)[(size_t)(gm + j) * N + gn] = __float2bfloat16(v);
                    else          ((float*)O0)[(size_t)(gm + j) * N + gn] = v;
                }
            }
        }
    }
}

// ---------------- per-head KV = K^T V (64x64) + ksum, bf16 in, fp32 atomics
#define KV_SLICES 16
__global__ __launch_bounds__(256) void kv_kernel(
    const bf16* __restrict__ k, const bf16* __restrict__ v,
    float* __restrict__ kv, float* __restrict__ ksum)
{
    __shared__ float Ks[16][68];
    __shared__ float Vs[16][68];
    int bh = blockIdx.x;           // 0..31  (= b*8 + h)
    int b = bh >> 3, h = bh & 7;
    int tid = threadIdx.x;
    int rbase = b * SEQ + blockIdx.y * (SEQ / KV_SLICES);
    int lr = tid >> 4;
    int lc = (tid & 15) * 4;
    int e  = tid & 63;
    int d0 = (tid >> 6) * 16;
    float acc[16] = {};
    float ks_acc = 0.f;
    for (int c = 0; c < SEQ / KV_SLICES; c += 16) {
        const ushort4 k4 = *(const ushort4*)(k + (size_t)(rbase + c + lr) * DIM + h * HD + lc);
        Ks[lr][lc + 0] = b2f(k4.x); Ks[lr][lc + 1] = b2f(k4.y);
        Ks[lr][lc + 2] = b2f(k4.z); Ks[lr][lc + 3] = b2f(k4.w);
        const ushort4 v4 = *(const ushort4*)(v + (size_t)(rbase + c + lr) * DIM + h * HD + lc);
        Vs[lr][lc + 0] = b2f(v4.x); Vs[lr][lc + 1] = b2f(v4.y);
        Vs[lr][lc + 2] = b2f(v4.z); Vs[lr][lc + 3] = b2f(v4.w);
        __syncthreads();
#pragma unroll
        for (int nn = 0; nn < 16; ++nn) {
            float vv = Vs[nn][e];
#pragma unroll
            for (int i = 0; i < 16; ++i)
                acc[i] += Ks[nn][d0 + i] * vv;
            if (d0 == 0) ks_acc += Ks[nn][e];
        }
        __syncthreads();
    }
    float* kvp = kv + (size_t)bh * (HD * HD);
#pragma unroll
    for (int i = 0; i < 16; ++i)
        atomicAdd(kvp + (d0 + i) * HD + e, acc[i]);   // kv[d][e]
    if (d0 == 0) atomicAdd(ksum + bh * HD + e, ks_acc);
}

// ---------------- denom[row][h] = q[row, h*64:].ksum[bh] ------------------
__global__ __launch_bounds__(256) void denom_kernel(
    const bf16* __restrict__ Q, const float* __restrict__ KS,
    float* __restrict__ denom)
{
    __shared__ float ks[512];
    int tid = threadIdx.x;
    int row0 = blockIdx.x * 4;
    int b = row0 >> 11;
    ks[tid]       = KS[b * 512 + tid];
    ks[tid + 256] = KS[b * 512 + tid + 256];
    __syncthreads();
    int row = row0 + (tid >> 6);
    int l = tid & 63;
    uint4 qu = *(const uint4*)(Q + (size_t)row * DIM + l * 8);
    float s = 0.f;
    const unsigned int* qw = (const unsigned int*)&qu;
    int cb = l * 8;
#pragma unroll
    for (int p = 0; p < 4; ++p) {
        s += __uint_as_float(qw[p] << 16)         * ks[cb + p * 2];
        s += __uint_as_float(qw[p] & 0xffff0000u) * ks[cb + p * 2 + 1];
    }
    s += __shfl_xor(s, 1, 64);
    s += __shfl_xor(s, 2, 64);
    s += __shfl_xor(s, 4, 64);
    if ((l & 7) == 0) denom[row * 8 + (l >> 3)] = s;
}

// ---------------- attn: out[128 rows, head] = Q_h @ KV_h^T / denom --------
__global__ __launch_bounds__(256) void attn_gemm(
    const bf16* __restrict__ Q, const float* __restrict__ KVg,
    const float* __restrict__ denom, bf16* __restrict__ out)
{
    __shared__ __align__(16) bf16 As[128][72];
    __shared__ __align__(16) bf16 Bs[64][72];
    int h = blockIdx.x;
    int m0 = blockIdx.y * 128;
    int bh = ((m0 >> 11) << 3) + h;
    int tid = threadIdx.x;
    int lane = tid & 63, wid = tid >> 6;
    {
        int r = tid >> 3, c0 = (tid & 7) * 8;
#pragma unroll
        for (int p = 0; p < 4; ++p) {
            int row = p * 32 + r;
            *(bf16x8*)&As[row][c0] =
                *(const bf16x8*)(Q + (size_t)(m0 + row) * DIM + h * HD + c0);
        }
        const float* kvp = KVg + (size_t)bh * (HD * HD);
        int e = tid & 63, d0 = (tid >> 6) * 16;
#pragma unroll
        for (int i = 0; i < 16; ++i)
            Bs[e][d0 + i] = __float2bfloat16(kvp[(d0 + i) * HD + e]);  // Bs[e][d]=KV[d][e]
    }
    __syncthreads();
    int la = lane & 15, ka = lane >> 4;
    f32x4 acc[2][4] = {};
#pragma unroll
    for (int s = 0; s < 2; ++s) {
        bf16x8 a[2], b[4];
#pragma unroll
        for (int m = 0; m < 2; ++m)
            a[m] = *(const bf16x8*)&As[wid * 32 + m * 16 + la][s * 32 + ka * 8];
#pragma unroll
        for (int n = 0; n < 4; ++n)
            b[n] = *(const bf16x8*)&Bs[n * 16 + la][s * 32 + ka * 8];
#pragma unroll
        for (int m = 0; m < 2; ++m)
#pragma unroll
            for (int n = 0; n < 4; ++n)
                acc[m][n] = __builtin_amdgcn_mfma_f32_16x16x32_bf16(a[m], b[n], acc[m][n], 0, 0, 0);
    }
    int rg = (lane >> 4) * 4;
#pragma unroll
    for (int m = 0; m < 2; ++m) {
#pragma unroll
        for (int j = 0; j < 4; ++j) {
            int gm = m0 + wid * 32 + m * 16 + rg + j;
            float rdn = 1.f / (denom[gm * 8 + h] + 1e-5f);
#pragma unroll
            for (int n = 0; n < 4; ++n) {
                int gn = h * HD + n * 16 + la;
                out[(size_t)gm * DIM + gn] = __float2bfloat16(acc[m][n][j] * rdn);
            }
        }
    }
}

extern "C" void kernel_launch(void* const* d_in, const int* in_sizes, int n_in,
                              void* d_out, int out_size, void* d_ws, size_t ws_size,
                              hipStream_t stream)
{
    const float* x   = (const float*)d_in[0];
    const float* Wq  = (const float*)d_in[1];
    const float* bq  = (const float*)d_in[2];
    const float* Wk  = (const float*)d_in[3];
    const float* bk  = (const float*)d_in[4];
    const float* Wv  = (const float*)d_in[5];
    const float* bv  = (const float*)d_in[6];
    const float* Wo  = (const float*)d_in[7];
    const float* bo  = (const float*)d_in[8];
    const float* W1  = (const float*)d_in[9];
    const float* b1  = (const float*)d_in[10];
    const float* W2  = (const float*)d_in[11];
    const float* b2  = (const float*)d_in[12];
    const float* g1  = (const float*)d_in[13];
    const float* be1 = (const float*)d_in[14];
    const float* g2  = (const float*)d_in[15];
    const float* be2 = (const float*)d_in[16];

    char* wsb = (char*)d_ws;
    const size_t MB = 1u << 20;
    bf16*  Qb  = (bf16*)(wsb + 0 * MB);      // 8 MB
    bf16*  Kbb = (bf16*)(wsb + 8 * MB);      // 8 MB
    bf16*  Vb  = (bf16*)(wsb + 16 * MB);     // 8 MB
    bf16*  xn  = (bf16*)(wsb + 24 * MB);     // 8 MB; attnb reuses after QKV
    float* y   = (float*)(wsb + 32 * MB);    // 16 MB
    bf16*  h   = (bf16*)(wsb + 48 * MB);     // 8 MB
    bf16*  F1  = (bf16*)(wsb + 0 * MB);      // 16 MB (over Qb+Kbb, free by then)
    bf16*  WqkvT = (bf16*)(wsb + 56 * MB);   // [1536][512] = 1.5 MB
    bf16*  WqT = WqkvT;
    bf16*  WkT = WqT + 512 * 512;
    bf16*  WvT = WkT + 512 * 512;
    bf16*  WoT = WvT + 512 * 512;            // 0.5 MB
    bf16*  W1T = WoT + 512 * 512;            // 1 MB  [1024][512]
    bf16*  W2T = W1T + 512 * 1024;           // 1 MB  [512][1024]
    float* KV  = (float*)(wsb + 60 * MB);    // 512 KB
    float* KS  = KV + 32 * HD * HD;          // 8 KB
    float* dnm = (float*)(wsb + 61 * MB);    // 256 KB
    bf16*  attnb = xn;

    float* out = (float*)d_out;
    dim3 blk(256);

    hipMemsetAsync(KV, 0, (size_t)(32 * HD * HD + 32 * HD) * sizeof(float), stream);
    // 0. weights -> bf16 [N][K]
    wtall_kernel<<<2048, blk, 0, stream>>>(Wq, Wk, Wv, Wo, W1, W2,
                                           WqT, WkT, WvT, WoT, W1T, W2T);
    // 1. xn = LN1(x)
    ln_kernel<<<2048, blk, 0, stream>>>(x, g1, be1, xn);
    // 2. fused q/k/v projection (N=1536)
    mfma_gemm128<1><<<dim3(12, 64), blk, 0, stream>>>(
        xn, WqkvT, bq, bk, bv, nullptr, Qb, Kbb, Vb, ROWS_TOTAL, 1536, 512, 0.125f);
    // 3. KV = K^T V + ksum
    kv_kernel<<<dim3(32, KV_SLICES), blk, 0, stream>>>(Kbb, Vb, KV, KS);
    // 4. denom
    denom_kernel<<<2048, blk, 0, stream>>>(Qb, KS, dnm);
    // 5. attn
    attn_gemm<<<dim3(8, 64), blk, 0, stream>>>(Qb, KV, dnm, attnb);
    // 6. y = x + attn @ Wo + bo
    mfma_gemm128<0><<<dim3(4, 64), blk, 0, stream>>>(
        attnb, WoT, bo, nullptr, nullptr, x, y, nullptr, nullptr, ROWS_TOTAL, 512, 512, 1.f);
    // 7. h = LN2(y)
    ln_kernel<<<2048, blk, 0, stream>>>(y, g2, be2, h);
    // 8. f1 = relu(h @ W1 + b1)
    mfma_gemm128<3><<<dim3(8, 64), blk, 0, stream>>>(
        h, W1T, b1, nullptr, nullptr, nullptr, F1, nullptr, nullptr, ROWS_TOTAL, 1024, 512, 1.f);
    // 9. out = y + f1 @ W2 + b2
    mfma_gemm128<0><<<dim3(4, 64), blk, 0, stream>>>(
        F1, W2T, b2, nullptr, nullptr, y, out, nullptr, nullptr, ROWS_TOTAL, 512, 1024, 1.f);
}

// Round 5
// 161.360 us; speedup vs baseline: 3.8823x; 1.1413x over previous
//
#include <hip/hip_runtime.h>
#include <hip/hip_bf16.h>
#include <math.h>

#define DIM 512
#define HEADS 8
#define HD 64
#define ROWS_TOTAL 8192   // 4 * 2048
#define SEQ 2048

typedef __hip_bfloat16 bf16;
typedef __bf16 bf16x8 __attribute__((ext_vector_type(8)));
typedef float f32x4 __attribute__((ext_vector_type(4)));

__device__ __forceinline__ float elu1(float x) {
    return x > 0.f ? x + 1.f : __expf(x);
}
__device__ __forceinline__ float b2f(unsigned short u) {
    return __uint_as_float(((unsigned int)u) << 16);
}
__device__ __forceinline__ void gl16(const void* g, void* l) {
    __builtin_amdgcn_global_load_lds(
        (const __attribute__((address_space(1))) void*)g,
        (__attribute__((address_space(3))) void*)l, 16, 0, 0);
}

// ---------------- LayerNorm: one wave per 512-wide row, bf16 output -------
__global__ __launch_bounds__(256) void ln_kernel(const float* __restrict__ x,
                                                 const float* __restrict__ g,
                                                 const float* __restrict__ b,
                                                 bf16* __restrict__ out)
{
    int row  = blockIdx.x * 4 + (threadIdx.x >> 6);
    int lane = threadIdx.x & 63;
    const float* xr = x + (size_t)row * DIM + lane * 8;
    float4 v1 = *(const float4*)xr;
    float4 v2 = *(const float4*)(xr + 4);
    float s  = v1.x + v1.y + v1.z + v1.w + v2.x + v2.y + v2.z + v2.w;
    float sq = v1.x*v1.x + v1.y*v1.y + v1.z*v1.z + v1.w*v1.w
             + v2.x*v2.x + v2.y*v2.y + v2.z*v2.z + v2.w*v2.w;
#pragma unroll
    for (int off = 32; off > 0; off >>= 1) {
        s  += __shfl_xor(s,  off, 64);
        sq += __shfl_xor(sq, off, 64);
    }
    float mean = s * (1.f / DIM);
    float var  = sq * (1.f / DIM) - mean * mean;
    float rstd = rsqrtf(var + 1e-5f);
    int c = lane * 8;
    float4 ga = *(const float4*)(g + c);
    float4 gb = *(const float4*)(g + c + 4);
    float4 ba = *(const float4*)(b + c);
    float4 bb = *(const float4*)(b + c + 4);
    bf16 ob[8];
    ob[0] = __float2bfloat16((v1.x - mean) * rstd * ga.x + ba.x);
    ob[1] = __float2bfloat16((v1.y - mean) * rstd * ga.y + ba.y);
    ob[2] = __float2bfloat16((v1.z - mean) * rstd * ga.z + ba.z);
    ob[3] = __float2bfloat16((v1.w - mean) * rstd * ga.w + ba.w);
    ob[4] = __float2bfloat16((v2.x - mean) * rstd * gb.x + bb.x);
    ob[5] = __float2bfloat16((v2.y - mean) * rstd * gb.y + bb.y);
    ob[6] = __float2bfloat16((v2.z - mean) * rstd * gb.z + bb.z);
    ob[7] = __float2bfloat16((v2.w - mean) * rstd * gb.w + bb.w);
    *(uint4*)(out + (size_t)row * DIM + c) = *(uint4*)ob;
}

// ---------------- transpose+convert all 6 weights: W[K][N] -> Wt[N][K] bf16
__global__ __launch_bounds__(256) void wtall_kernel(
    const float* __restrict__ Wq, const float* __restrict__ Wk,
    const float* __restrict__ Wv, const float* __restrict__ Wo,
    const float* __restrict__ W1, const float* __restrict__ W2,
    bf16* WqT, bf16* WkT, bf16* WvT, bf16* WoT, bf16* W1T, bf16* W2T)
{
    __shared__ float t[32][33];
    int bx = blockIdx.x;
    const float* W; bf16* T; int K, N, tk, tn;
    if (bx < 1024) {
        int m = bx >> 8, tix = bx & 255;
        const float* ws_[4] = {Wq, Wk, Wv, Wo};
        bf16* ts_[4] = {WqT, WkT, WvT, WoT};
        W = ws_[m]; T = ts_[m]; K = 512; N = 512; tn = tix & 15; tk = tix >> 4;
    } else if (bx < 1536) {
        int tix = bx - 1024; W = W1; T = W1T; K = 512; N = 1024; tn = tix & 31; tk = tix >> 5;
    } else {
        int tix = bx - 1536; W = W2; T = W2T; K = 1024; N = 512; tn = tix & 15; tk = tix >> 4;
    }
    int n0 = tn * 32, k0 = tk * 32;
    int tx = threadIdx.x & 31, ty = threadIdx.x >> 5;   // ty 0..7
#pragma unroll
    for (int i = 0; i < 32; i += 8)
        t[ty + i][tx] = W[(size_t)(k0 + ty + i) * N + n0 + tx];
    __syncthreads();
#pragma unroll
    for (int i = 0; i < 32; i += 8)
        T[(size_t)(n0 + ty + i) * K + k0 + tx] = __float2bfloat16(t[tx][ty + i]);
}

// ---------------- 128xBN bf16 MFMA GEMM, double-buffered (T3 2-phase) -----
// Wave grid 2x2; each wave computes 64 rows x (BN/2) cols = 4 x (BN/32) frags.
// EPI 0: fp32 out (+resid opt).  EPI 1: QKV-split bf16 out.  EPI 3: relu bf16.
template<int BN, int EPI>
__global__ __launch_bounds__(256) void mfma_gemm(
    const bf16* __restrict__ A, const bf16* __restrict__ Bt,
    const float* __restrict__ b0, const float* __restrict__ b1,
    const float* __restrict__ b2, const float* __restrict__ resid,
    void* __restrict__ O0, void* __restrict__ O1, void* __restrict__ O2,
    int N, int K, float scale)
{
    constexpr int NW = BN / 32;   // n-frags per wave (wave covers 64 x (BN/2))
    __shared__ __align__(16) bf16 As[2][128 * 32];
    __shared__ __align__(16) bf16 Bs[2][BN * 32];
    int tid = threadIdx.x;
    int lane = tid & 63, wid = tid >> 6;
    int wr = wid >> 1, wc = wid & 1;
    int m0 = blockIdx.y * 128, n0 = blockIdx.x * BN;
    int sr = tid >> 2;              // 0..63 staging row
    int sc = (tid & 3) * 8;         // staging col (bf16)
    const bf16* ga = A  + (size_t)(m0 + sr) * K + sc;
    const bf16* gb = Bt + (size_t)(n0 + sr) * K + sc;
    f32x4 acc[4][NW] = {};
    int la = lane & 15, ka = lane >> 4;
    int nt = K / 32;

    // prologue: stage tile 0 into buffer 0
    gl16(ga, &As[0][tid * 8]);
    gl16(ga + (size_t)64 * K, &As[0][tid * 8 + 2048]);
    gl16(gb, &Bs[0][tid * 8]);
    if constexpr (BN == 128) gl16(gb + (size_t)64 * K, &Bs[0][tid * 8 + 2048]);
    __syncthreads();

    for (int t = 0; t < nt; ++t) {
        int cur = t & 1;
        if (t + 1 < nt) {                       // prefetch next tile
            int k0 = (t + 1) * 32;
            gl16(ga + k0, &As[cur ^ 1][tid * 8]);
            gl16(ga + (size_t)64 * K + k0, &As[cur ^ 1][tid * 8 + 2048]);
            gl16(gb + k0, &Bs[cur ^ 1][tid * 8]);
            if constexpr (BN == 128) gl16(gb + (size_t)64 * K + k0, &Bs[cur ^ 1][tid * 8 + 2048]);
        }
        const bf16x8* Av = (const bf16x8*)As[cur];
        const bf16x8* Bv = (const bf16x8*)Bs[cur];
        bf16x8 a[4], b[NW];
#pragma unroll
        for (int m = 0; m < 4; ++m) a[m] = Av[(wr * 64 + m * 16 + la) * 4 + ka];
#pragma unroll
        for (int n = 0; n < NW; ++n) b[n] = Bv[(wc * (BN / 2) + n * 16 + la) * 4 + ka];
#pragma unroll
        for (int m = 0; m < 4; ++m)
#pragma unroll
            for (int n = 0; n < NW; ++n)
                acc[m][n] = __builtin_amdgcn_mfma_f32_16x16x32_bf16(a[m], b[n], acc[m][n], 0, 0, 0);
        __syncthreads();   // drains prefetch (vmcnt) + protects buffers
    }

    int rg = (lane >> 4) * 4;
    if (EPI == 1) {
        // QKV split: bx 0-3 -> q(elu1(v*scale)), 4-7 -> k(elu1), 8-11 -> v(none)
        int bsel = blockIdx.x >> 2;
        bf16* Ob = (bf16*)(bsel == 0 ? O0 : (bsel == 1 ? O1 : O2));
        const float* bb = bsel == 0 ? b0 : (bsel == 1 ? b1 : b2);
        int nloc0 = (blockIdx.x & 3) * 128;
#pragma unroll
        for (int m = 0; m < 4; ++m) {
            int gm = m0 + wr * 64 + m * 16 + rg;
#pragma unroll
            for (int n = 0; n < NW; ++n) {
                int gnl = nloc0 + wc * (BN / 2) + n * 16 + la;
                float bv_ = bb[gnl];
#pragma unroll
                for (int j = 0; j < 4; ++j) {
                    float v = acc[m][n][j] + bv_;
                    if (bsel == 0)      v = elu1(v * scale);
                    else if (bsel == 1) v = elu1(v);
                    Ob[(size_t)(gm + j) * 512 + gnl] = __float2bfloat16(v);
                }
            }
        }
    } else {
#pragma unroll
        for (int m = 0; m < 4; ++m) {
            int gm = m0 + wr * 64 + m * 16 + rg;
#pragma unroll
            for (int n = 0; n < NW; ++n) {
                int gn = n0 + wc * (BN / 2) + n * 16 + la;
                float bv_ = b0[gn];
#pragma unroll
                for (int j = 0; j < 4; ++j) {
                    float v = acc[m][n][j] + bv_;
                    if (EPI == 3) v = fmaxf(v, 0.f);
                    if (resid) v += resid[(size_t)(gm + j) * N + gn];
                    if (EPI == 3) ((bf16*)O0)[(size_t)(gm + j) * N + gn] = __float2bfloat16(v);
                    else          ((float*)O0)[(size_t)(gm + j) * N + gn] = v;
                }
            }
        }
    }
}

// ---------------- per-head KV = K^T V (64x64) + ksum, bf16 in, fp32 atomics
#define KV_SLICES 16
__global__ __launch_bounds__(256) void kv_kernel(
    const bf16* __restrict__ k, const bf16* __restrict__ v,
    float* __restrict__ kv, float* __restrict__ ksum)
{
    __shared__ float Ks[16][68];
    __shared__ float Vs[16][68];
    int bh = blockIdx.x;           // 0..31  (= b*8 + h)
    int b = bh >> 3, h = bh & 7;
    int tid = threadIdx.x;
    int rbase = b * SEQ + blockIdx.y * (SEQ / KV_SLICES);
    int lr = tid >> 4;
    int lc = (tid & 15) * 4;
    int e  = tid & 63;
    int d0 = (tid >> 6) * 16;
    float acc[16] = {};
    float ks_acc = 0.f;
    for (int c = 0; c < SEQ / KV_SLICES; c += 16) {
        const ushort4 k4 = *(const ushort4*)(k + (size_t)(rbase + c + lr) * DIM + h * HD + lc);
        Ks[lr][lc + 0] = b2f(k4.x); Ks[lr][lc + 1] = b2f(k4.y);
        Ks[lr][lc + 2] = b2f(k4.z); Ks[lr][lc + 3] = b2f(k4.w);
        const ushort4 v4 = *(const ushort4*)(v + (size_t)(rbase + c + lr) * DIM + h * HD + lc);
        Vs[lr][lc + 0] = b2f(v4.x); Vs[lr][lc + 1] = b2f(v4.y);
        Vs[lr][lc + 2] = b2f(v4.z); Vs[lr][lc + 3] = b2f(v4.w);
        __syncthreads();
#pragma unroll
        for (int nn = 0; nn < 16; ++nn) {
            float vv = Vs[nn][e];
#pragma unroll
            for (int i = 0; i < 16; ++i)
                acc[i] += Ks[nn][d0 + i] * vv;
            if (d0 == 0) ks_acc += Ks[nn][e];
        }
        __syncthreads();
    }
    float* kvp = kv + (size_t)bh * (HD * HD);
#pragma unroll
    for (int i = 0; i < 16; ++i)
        atomicAdd(kvp + (d0 + i) * HD + e, acc[i]);   // kv[d][e]
    if (d0 == 0) atomicAdd(ksum + bh * HD + e, ks_acc);
}

// ---- attn: out[128 rows, head] = (Q_h @ KV_h^T) / (Q_h . ksum_h + 1e-5) --
__global__ __launch_bounds__(256) void attn_gemm(
    const bf16* __restrict__ Q, const float* __restrict__ KVg,
    const float* __restrict__ KS, bf16* __restrict__ out)
{
    __shared__ __align__(16) bf16 As[128][72];
    __shared__ __align__(16) bf16 Bs[64][72];
    __shared__ float ks[64];
    __shared__ float dn[128];
    int h = blockIdx.x;
    int m0 = blockIdx.y * 128;
    int bh = ((m0 >> 11) << 3) + h;
    int tid = threadIdx.x;
    int lane = tid & 63, wid = tid >> 6;
    {
        int r = tid >> 3, c0 = (tid & 7) * 8;
#pragma unroll
        for (int p = 0; p < 4; ++p) {
            int row = p * 32 + r;
            *(bf16x8*)&As[row][c0] =
                *(const bf16x8*)(Q + (size_t)(m0 + row) * DIM + h * HD + c0);
        }
        const float* kvp = KVg + (size_t)bh * (HD * HD);
        int e = tid & 63, d0 = (tid >> 6) * 16;
#pragma unroll
        for (int i = 0; i < 16; ++i)
            Bs[e][d0 + i] = __float2bfloat16(kvp[(d0 + i) * HD + e]);  // Bs[e][d]=KV[d][e]
        if (tid < 64) ks[tid] = KS[bh * HD + tid];
    }
    __syncthreads();
    // denom: 128 threads, one row each: q_h[row] . ksum_h
    if (tid < 128) {
        float s = 0.f;
#pragma unroll
        for (int c = 0; c < 8; ++c) {
            bf16x8 qv = *(const bf16x8*)&As[tid][c * 8];
#pragma unroll
            for (int j = 0; j < 8; ++j)
                s += (float)qv[j] * ks[c * 8 + j];
        }
        dn[tid] = 1.f / (s + 1e-5f);
    }
    int la = lane & 15, ka = lane >> 4;
    f32x4 acc[2][4] = {};
#pragma unroll
    for (int s = 0; s < 2; ++s) {
        bf16x8 a[2], b[4];
#pragma unroll
        for (int m = 0; m < 2; ++m)
            a[m] = *(const bf16x8*)&As[wid * 32 + m * 16 + la][s * 32 + ka * 8];
#pragma unroll
        for (int n = 0; n < 4; ++n)
            b[n] = *(const bf16x8*)&Bs[n * 16 + la][s * 32 + ka * 8];
#pragma unroll
        for (int m = 0; m < 2; ++m)
#pragma unroll
            for (int n = 0; n < 4; ++n)
                acc[m][n] = __builtin_amdgcn_mfma_f32_16x16x32_bf16(a[m], b[n], acc[m][n], 0, 0, 0);
    }
    __syncthreads();   // dn visible
    int rg = (lane >> 4) * 4;
#pragma unroll
    for (int m = 0; m < 2; ++m) {
#pragma unroll
        for (int j = 0; j < 4; ++j) {
            int lr = wid * 32 + m * 16 + rg + j;
            float rdn = dn[lr];
            int gm = m0 + lr;
#pragma unroll
            for (int n = 0; n < 4; ++n) {
                int gn = h * HD + n * 16 + la;
                out[(size_t)gm * DIM + gn] = __float2bfloat16(acc[m][n][j] * rdn);
            }
        }
    }
}

extern "C" void kernel_launch(void* const* d_in, const int* in_sizes, int n_in,
                              void* d_out, int out_size, void* d_ws, size_t ws_size,
                              hipStream_t stream)
{
    const float* x   = (const float*)d_in[0];
    const float* Wq  = (const float*)d_in[1];
    const float* bq  = (const float*)d_in[2];
    const float* Wk  = (const float*)d_in[3];
    const float* bk  = (const float*)d_in[4];
    const float* Wv  = (const float*)d_in[5];
    const float* bv  = (const float*)d_in[6];
    const float* Wo  = (const float*)d_in[7];
    const float* bo  = (const float*)d_in[8];
    const float* W1  = (const float*)d_in[9];
    const float* b1  = (const float*)d_in[10];
    const float* W2  = (const float*)d_in[11];
    const float* b2  = (const float*)d_in[12];
    const float* g1  = (const float*)d_in[13];
    const float* be1 = (const float*)d_in[14];
    const float* g2  = (const float*)d_in[15];
    const float* be2 = (const float*)d_in[16];

    char* wsb = (char*)d_ws;
    const size_t MB = 1u << 20;
    bf16*  Qb  = (bf16*)(wsb + 0 * MB);      // 8 MB
    bf16*  Kbb = (bf16*)(wsb + 8 * MB);      // 8 MB
    bf16*  Vb  = (bf16*)(wsb + 16 * MB);     // 8 MB
    bf16*  xn  = (bf16*)(wsb + 24 * MB);     // 8 MB; attnb reuses after QKV
    float* y   = (float*)(wsb + 32 * MB);    // 16 MB
    bf16*  h   = (bf16*)(wsb + 48 * MB);     // 8 MB
    bf16*  F1  = (bf16*)(wsb + 0 * MB);      // 16 MB (over Qb+Kbb, free by then)
    bf16*  WqkvT = (bf16*)(wsb + 56 * MB);   // [1536][512] = 1.5 MB
    bf16*  WoT = WqkvT + 3 * 512 * 512;      // 0.5 MB
    bf16*  W1T = WoT + 512 * 512;            // 1 MB  [1024][512]
    bf16*  W2T = W1T + 512 * 1024;           // 1 MB  [512][1024]
    float* KV  = (float*)(wsb + 60 * MB);    // 512 KB
    float* KS  = KV + 32 * HD * HD;          // 8 KB
    bf16*  attnb = xn;

    float* out = (float*)d_out;
    dim3 blk(256);

    hipMemsetAsync(KV, 0, (size_t)(32 * HD * HD + 32 * HD) * sizeof(float), stream);
    // 0. weights -> bf16 [N][K]
    wtall_kernel<<<2048, blk, 0, stream>>>(Wq, Wk, Wv, Wo, W1, W2,
                                           WqkvT, WqkvT + 512 * 512, WqkvT + 2 * 512 * 512,
                                           WoT, W1T, W2T);
    // 1. xn = LN1(x)
    ln_kernel<<<2048, blk, 0, stream>>>(x, g1, be1, xn);
    // 2. fused q/k/v projection (N=1536)
    mfma_gemm<128, 1><<<dim3(12, 64), blk, 0, stream>>>(
        xn, WqkvT, bq, bk, bv, nullptr, Qb, Kbb, Vb, 1536, 512, 0.125f);
    // 3. KV = K^T V + ksum
    kv_kernel<<<dim3(32, KV_SLICES), blk, 0, stream>>>(Kbb, Vb, KV, KS);
    // 4. attn (denom fused)
    attn_gemm<<<dim3(8, 64), blk, 0, stream>>>(Qb, KV, KS, attnb);
    // 5. y = x + attn @ Wo + bo
    mfma_gemm<64, 0><<<dim3(8, 64), blk, 0, stream>>>(
        attnb, WoT, bo, nullptr, nullptr, x, y, nullptr, nullptr, 512, 512, 1.f);
    // 6. h = LN2(y)
    ln_kernel<<<2048, blk, 0, stream>>>(y, g2, be2, h);
    // 7. f1 = relu(h @ W1 + b1)
    mfma_gemm<128, 3><<<dim3(8, 64), blk, 0, stream>>>(
        h, W1T, b1, nullptr, nullptr, nullptr, F1, nullptr, nullptr, 1024, 512, 1.f);
    // 8. out = y + f1 @ W2 + b2
    mfma_gemm<64, 0><<<dim3(8, 64), blk, 0, stream>>>(
        F1, W2T, b2, nullptr, nullptr, y, out, nullptr, nullptr, 512, 1024, 1.f);
}

// Round 6
// 157.238 us; speedup vs baseline: 3.9841x; 1.0262x over previous
//
#include <hip/hip_runtime.h>
#include <hip/hip_bf16.h>
#include <math.h>

#define DIM 512
#define HEADS 8
#define HD 64
#define ROWS_TOTAL 8192   // 4 * 2048
#define SEQ 2048
#define NSLICE 8          // kv partial slices

typedef __hip_bfloat16 bf16;
typedef __bf16 bf16x8 __attribute__((ext_vector_type(8)));
typedef float f32x4 __attribute__((ext_vector_type(4)));

__device__ __forceinline__ float elu1(float x) {
    return x > 0.f ? x + 1.f : __expf(x);
}
__device__ __forceinline__ float b2f(unsigned short u) {
    return __uint_as_float(((unsigned int)u) << 16);
}
__device__ __forceinline__ void gl16(const void* g, void* l) {
    __builtin_amdgcn_global_load_lds(
        (const __attribute__((address_space(1))) void*)g,
        (__attribute__((address_space(3))) void*)l, 16, 0, 0);
}

// ---------------- LayerNorm: one wave per 512-wide row, bf16 output -------
__global__ __launch_bounds__(256) void ln_kernel(const float* __restrict__ x,
                                                 const float* __restrict__ g,
                                                 const float* __restrict__ b,
                                                 bf16* __restrict__ out)
{
    int row  = blockIdx.x * 4 + (threadIdx.x >> 6);
    int lane = threadIdx.x & 63;
    const float* xr = x + (size_t)row * DIM + lane * 8;
    float4 v1 = *(const float4*)xr;
    float4 v2 = *(const float4*)(xr + 4);
    float s  = v1.x + v1.y + v1.z + v1.w + v2.x + v2.y + v2.z + v2.w;
    float sq = v1.x*v1.x + v1.y*v1.y + v1.z*v1.z + v1.w*v1.w
             + v2.x*v2.x + v2.y*v2.y + v2.z*v2.z + v2.w*v2.w;
#pragma unroll
    for (int off = 32; off > 0; off >>= 1) {
        s  += __shfl_xor(s,  off, 64);
        sq += __shfl_xor(sq, off, 64);
    }
    float mean = s * (1.f / DIM);
    float var  = sq * (1.f / DIM) - mean * mean;
    float rstd = rsqrtf(var + 1e-5f);
    int c = lane * 8;
    float4 ga = *(const float4*)(g + c);
    float4 gb = *(const float4*)(g + c + 4);
    float4 ba = *(const float4*)(b + c);
    float4 bb = *(const float4*)(b + c + 4);
    bf16 ob[8];
    ob[0] = __float2bfloat16((v1.x - mean) * rstd * ga.x + ba.x);
    ob[1] = __float2bfloat16((v1.y - mean) * rstd * ga.y + ba.y);
    ob[2] = __float2bfloat16((v1.z - mean) * rstd * ga.z + ba.z);
    ob[3] = __float2bfloat16((v1.w - mean) * rstd * ga.w + ba.w);
    ob[4] = __float2bfloat16((v2.x - mean) * rstd * gb.x + bb.x);
    ob[5] = __float2bfloat16((v2.y - mean) * rstd * gb.y + bb.y);
    ob[6] = __float2bfloat16((v2.z - mean) * rstd * gb.z + bb.z);
    ob[7] = __float2bfloat16((v2.w - mean) * rstd * gb.w + bb.w);
    *(uint4*)(out + (size_t)row * DIM + c) = *(uint4*)ob;
}

// ---------------- transpose+convert all 6 weights: W[K][N] -> Wt[N][K] bf16
__global__ __launch_bounds__(256) void wtall_kernel(
    const float* __restrict__ Wq, const float* __restrict__ Wk,
    const float* __restrict__ Wv, const float* __restrict__ Wo,
    const float* __restrict__ W1, const float* __restrict__ W2,
    bf16* WqT, bf16* WkT, bf16* WvT, bf16* WoT, bf16* W1T, bf16* W2T)
{
    __shared__ float t[32][33];
    int bx = blockIdx.x;
    const float* W; bf16* T; int K, N, tk, tn;
    if (bx < 1024) {
        int m = bx >> 8, tix = bx & 255;
        const float* ws_[4] = {Wq, Wk, Wv, Wo};
        bf16* ts_[4] = {WqT, WkT, WvT, WoT};
        W = ws_[m]; T = ts_[m]; K = 512; N = 512; tn = tix & 15; tk = tix >> 4;
    } else if (bx < 1536) {
        int tix = bx - 1024; W = W1; T = W1T; K = 512; N = 1024; tn = tix & 31; tk = tix >> 5;
    } else {
        int tix = bx - 1536; W = W2; T = W2T; K = 1024; N = 512; tn = tix & 15; tk = tix >> 4;
    }
    int n0 = tn * 32, k0 = tk * 32;
    int tx = threadIdx.x & 31, ty = threadIdx.x >> 5;   // ty 0..7
#pragma unroll
    for (int i = 0; i < 32; i += 8)
        t[ty + i][tx] = W[(size_t)(k0 + ty + i) * N + n0 + tx];
    __syncthreads();
#pragma unroll
    for (int i = 0; i < 32; i += 8)
        T[(size_t)(n0 + ty + i) * K + k0 + tx] = __float2bfloat16(t[tx][ty + i]);
}

// ------- 128xBN bf16 MFMA GEMM, BK=64, double-buffered, XCD-swizzled ------
// 1D grid (gx*gy), GX = n-tiles. Wave grid 2x2: 64 rows x (BN/2) cols each.
// EPI 0: fp32 out (+resid opt).  EPI 1: QKV-split bf16 out.  EPI 3: relu bf16.
template<int BN, int EPI>
__global__ __launch_bounds__(256) void mfma_gemm(
    const bf16* __restrict__ A, const bf16* __restrict__ Bt,
    const float* __restrict__ b0, const float* __restrict__ b1,
    const float* __restrict__ b2, const float* __restrict__ resid,
    void* __restrict__ O0, void* __restrict__ O1, void* __restrict__ O2,
    int N, int K, int GX, float scale)
{
    constexpr int NW = BN / 32;     // n-frags per wave
    constexpr int NBL = BN / 32;    // B staging loads
    __shared__ __align__(16) bf16 As[2][128 * 64];
    __shared__ __align__(16) bf16 Bs[2][BN * 64];
    int tid = threadIdx.x;
    int lane = tid & 63, wid = tid >> 6;
    int wr = wid >> 1, wc = wid & 1;
    // XCD-aware swizzle: XCD x owns contiguous work chunk (gridDim.x % 8 == 0)
    int cpx = gridDim.x >> 3;
    int work = (blockIdx.x & 7) * cpx + (blockIdx.x >> 3);
    int bx = work % GX, by = work / GX;
    int m0 = by * 128, n0 = bx * BN;
    int sr = tid >> 3;              // 0..31 staging row
    int sc = (tid & 7) * 8;         // staging col (bf16)
    const bf16* ga = A  + (size_t)(m0 + sr) * K + sc;
    const bf16* gb = Bt + (size_t)(n0 + sr) * K + sc;
    f32x4 acc[4][NW] = {};
    int la = lane & 15, ka = lane >> 4;
    int nt = K >> 6;

    // prologue: stage tile 0 into buffer 0
#pragma unroll
    for (int j = 0; j < 4; ++j)
        gl16(ga + (size_t)j * 32 * K, &As[0][tid * 8 + j * 2048]);
#pragma unroll
    for (int j = 0; j < NBL; ++j)
        gl16(gb + (size_t)j * 32 * K, &Bs[0][tid * 8 + j * 2048]);
    __syncthreads();

    for (int t = 0; t < nt; ++t) {
        int cur = t & 1;
        if (t + 1 < nt) {                       // prefetch next K-tile
            int k0 = (t + 1) << 6;
#pragma unroll
            for (int j = 0; j < 4; ++j)
                gl16(ga + (size_t)j * 32 * K + k0, &As[cur ^ 1][tid * 8 + j * 2048]);
#pragma unroll
            for (int j = 0; j < NBL; ++j)
                gl16(gb + (size_t)j * 32 * K + k0, &Bs[cur ^ 1][tid * 8 + j * 2048]);
        }
        bf16x8 a[2][4], b[2][NW];
#pragma unroll
        for (int kk = 0; kk < 2; ++kk) {
#pragma unroll
            for (int m = 0; m < 4; ++m)
                a[kk][m] = *(const bf16x8*)&As[cur][(wr * 64 + m * 16 + la) * 64 + kk * 32 + ka * 8];
#pragma unroll
            for (int n = 0; n < NW; ++n)
                b[kk][n] = *(const bf16x8*)&Bs[cur][(wc * (BN / 2) + n * 16 + la) * 64 + kk * 32 + ka * 8];
        }
#pragma unroll
        for (int kk = 0; kk < 2; ++kk)
#pragma unroll
            for (int m = 0; m < 4; ++m)
#pragma unroll
                for (int n = 0; n < NW; ++n)
                    acc[m][n] = __builtin_amdgcn_mfma_f32_16x16x32_bf16(a[kk][m], b[kk][n], acc[m][n], 0, 0, 0);
        __syncthreads();   // drains prefetch (vmcnt) + protects buffers
    }

    int rg = (lane >> 4) * 4;
    if (EPI == 1) {
        // QKV split: bx 0-3 -> q(elu1(v*scale)), 4-7 -> k(elu1), 8-11 -> v(none)
        int bsel = bx >> 2;
        bf16* Ob = (bf16*)(bsel == 0 ? O0 : (bsel == 1 ? O1 : O2));
        const float* bb = bsel == 0 ? b0 : (bsel == 1 ? b1 : b2);
        int nloc0 = (bx & 3) * 128;
#pragma unroll
        for (int m = 0; m < 4; ++m) {
            int gm = m0 + wr * 64 + m * 16 + rg;
#pragma unroll
            for (int n = 0; n < NW; ++n) {
                int gnl = nloc0 + wc * (BN / 2) + n * 16 + la;
                float bv_ = bb[gnl];
#pragma unroll
                for (int j = 0; j < 4; ++j) {
                    float v = acc[m][n][j] + bv_;
                    if (bsel == 0)      v = elu1(v * scale);
                    else if (bsel == 1) v = elu1(v);
                    Ob[(size_t)(gm + j) * 512 + gnl] = __float2bfloat16(v);
                }
            }
        }
    } else {
#pragma unroll
        for (int m = 0; m < 4; ++m) {
            int gm = m0 + wr * 64 + m * 16 + rg;
#pragma unroll
            for (int n = 0; n < NW; ++n) {
                int gn = n0 + wc * (BN / 2) + n * 16 + la;
                float bv_ = b0[gn];
#pragma unroll
                for (int j = 0; j < 4; ++j) {
                    float v = acc[m][n][j] + bv_;
                    if (EPI == 3) v = fmaxf(v, 0.f);
                    if (resid) v += resid[(size_t)(gm + j) * N + gn];
                    if (EPI == 3) ((bf16*)O0)[(size_t)(gm + j) * N + gn] = __float2bfloat16(v);
                    else          ((float*)O0)[(size_t)(gm + j) * N + gn] = v;
                }
            }
        }
    }
}

// ---- per-head KV partials: KVp[slice][bh][d][e], KSp[slice][bh][e] -------
__global__ __launch_bounds__(256) void kv_kernel(
    const bf16* __restrict__ k, const bf16* __restrict__ v,
    float* __restrict__ KVp, float* __restrict__ KSp)
{
    __shared__ float Ks[16][68];
    __shared__ float Vs[16][68];
    int bh = blockIdx.x;           // 0..31  (= b*8 + h)
    int sl = blockIdx.y;           // 0..NSLICE-1
    int b = bh >> 3, h = bh & 7;
    int tid = threadIdx.x;
    int rbase = b * SEQ + sl * (SEQ / NSLICE);
    int lr = tid >> 4;
    int lc = (tid & 15) * 4;
    int e  = tid & 63;
    int d0 = (tid >> 6) * 16;
    float acc[16] = {};
    float ks_acc = 0.f;
    for (int c = 0; c < SEQ / NSLICE; c += 16) {
        const ushort4 k4 = *(const ushort4*)(k + (size_t)(rbase + c + lr) * DIM + h * HD + lc);
        Ks[lr][lc + 0] = b2f(k4.x); Ks[lr][lc + 1] = b2f(k4.y);
        Ks[lr][lc + 2] = b2f(k4.z); Ks[lr][lc + 3] = b2f(k4.w);
        const ushort4 v4 = *(const ushort4*)(v + (size_t)(rbase + c + lr) * DIM + h * HD + lc);
        Vs[lr][lc + 0] = b2f(v4.x); Vs[lr][lc + 1] = b2f(v4.y);
        Vs[lr][lc + 2] = b2f(v4.z); Vs[lr][lc + 3] = b2f(v4.w);
        __syncthreads();
#pragma unroll
        for (int nn = 0; nn < 16; ++nn) {
            float vv = Vs[nn][e];
#pragma unroll
            for (int i = 0; i < 16; ++i)
                acc[i] += Ks[nn][d0 + i] * vv;
            if (d0 == 0) ks_acc += Ks[nn][e];
        }
        __syncthreads();
    }
    float* kvp = KVp + ((size_t)sl * 32 + bh) * (HD * HD);
#pragma unroll
    for (int i = 0; i < 16; ++i)
        kvp[(d0 + i) * HD + e] = acc[i];   // kv[d][e]
    if (d0 == 0) KSp[((size_t)sl * 32 + bh) * HD + e] = ks_acc;
}

// ---- attn: out[128 rows, head] = (Q_h @ KV_h^T) / (Q_h . ksum_h + 1e-5) --
// KV/KS reduced over NSLICE partials during the LDS load.
__global__ __launch_bounds__(256) void attn_gemm(
    const bf16* __restrict__ Q, const float* __restrict__ KVp,
    const float* __restrict__ KSp, bf16* __restrict__ out)
{
    __shared__ __align__(16) bf16 As[128][72];
    __shared__ __align__(16) bf16 Bs[64][72];
    __shared__ float ks[64];
    __shared__ float dn[128];
    int h = blockIdx.x;
    int m0 = blockIdx.y * 128;
    int bh = ((m0 >> 11) << 3) + h;
    int tid = threadIdx.x;
    int lane = tid & 63, wid = tid >> 6;
    {
        int r = tid >> 3, c0 = (tid & 7) * 8;
#pragma unroll
        for (int p = 0; p < 4; ++p) {
            int row = p * 32 + r;
            *(bf16x8*)&As[row][c0] =
                *(const bf16x8*)(Q + (size_t)(m0 + row) * DIM + h * HD + c0);
        }
        const float* kvb = KVp + (size_t)bh * (HD * HD);
        int e = tid & 63, d0 = (tid >> 6) * 16;
        float s_[16] = {};
#pragma unroll
        for (int sl = 0; sl < NSLICE; ++sl)
#pragma unroll
            for (int i = 0; i < 16; ++i)
                s_[i] += kvb[(size_t)sl * 32 * (HD * HD) + (d0 + i) * HD + e];
#pragma unroll
        for (int i = 0; i < 16; ++i)
            Bs[e][d0 + i] = __float2bfloat16(s_[i]);   // Bs[e][d]=KV[d][e]
        if (tid < 64) {
            float s = 0.f;
#pragma unroll
            for (int sl = 0; sl < NSLICE; ++sl)
                s += KSp[((size_t)sl * 32 + bh) * HD + tid];
            ks[tid] = s;
        }
    }
    __syncthreads();
    // denom: 128 threads, one row each: q_h[row] . ksum_h
    if (tid < 128) {
        float s = 0.f;
#pragma unroll
        for (int c = 0; c < 8; ++c) {
            bf16x8 qv = *(const bf16x8*)&As[tid][c * 8];
#pragma unroll
            for (int j = 0; j < 8; ++j)
                s += (float)qv[j] * ks[c * 8 + j];
        }
        dn[tid] = 1.f / (s + 1e-5f);
    }
    int la = lane & 15, ka = lane >> 4;
    f32x4 acc[2][4] = {};
#pragma unroll
    for (int s = 0; s < 2; ++s) {
        bf16x8 a[2], b[4];
#pragma unroll
        for (int m = 0; m < 2; ++m)
            a[m] = *(const bf16x8*)&As[wid * 32 + m * 16 + la][s * 32 + ka * 8];
#pragma unroll
        for (int n = 0; n < 4; ++n)
            b[n] = *(const bf16x8*)&Bs[n * 16 + la][s * 32 + ka * 8];
#pragma unroll
        for (int m = 0; m < 2; ++m)
#pragma unroll
            for (int n = 0; n < 4; ++n)
                acc[m][n] = __builtin_amdgcn_mfma_f32_16x16x32_bf16(a[m], b[n], acc[m][n], 0, 0, 0);
    }
    __syncthreads();   // dn visible
    int rg = (lane >> 4) * 4;
#pragma unroll
    for (int m = 0; m < 2; ++m) {
#pragma unroll
        for (int j = 0; j < 4; ++j) {
            int lr = wid * 32 + m * 16 + rg + j;
            float rdn = dn[lr];
            int gm = m0 + lr;
#pragma unroll
            for (int n = 0; n < 4; ++n) {
                int gn = h * HD + n * 16 + la;
                out[(size_t)gm * DIM + gn] = __float2bfloat16(acc[m][n][j] * rdn);
            }
        }
    }
}

extern "C" void kernel_launch(void* const* d_in, const int* in_sizes, int n_in,
                              void* d_out, int out_size, void* d_ws, size_t ws_size,
                              hipStream_t stream)
{
    const float* x   = (const float*)d_in[0];
    const float* Wq  = (const float*)d_in[1];
    const float* bq  = (const float*)d_in[2];
    const float* Wk  = (const float*)d_in[3];
    const float* bk  = (const float*)d_in[4];
    const float* Wv  = (const float*)d_in[5];
    const float* bv  = (const float*)d_in[6];
    const float* Wo  = (const float*)d_in[7];
    const float* bo  = (const float*)d_in[8];
    const float* W1  = (const float*)d_in[9];
    const float* b1  = (const float*)d_in[10];
    const float* W2  = (const float*)d_in[11];
    const float* b2  = (const float*)d_in[12];
    const float* g1  = (const float*)d_in[13];
    const float* be1 = (const float*)d_in[14];
    const float* g2  = (const float*)d_in[15];
    const float* be2 = (const float*)d_in[16];

    char* wsb = (char*)d_ws;
    const size_t MB = 1u << 20;
    bf16*  Qb  = (bf16*)(wsb + 0 * MB);      // 8 MB
    bf16*  Kbb = (bf16*)(wsb + 8 * MB);      // 8 MB
    bf16*  Vb  = (bf16*)(wsb + 16 * MB);     // 8 MB
    bf16*  xn  = (bf16*)(wsb + 24 * MB);     // 8 MB; attnb reuses after QKV
    bf16*  h   = (bf16*)(wsb + 32 * MB);     // 8 MB
    bf16*  WqkvT = (bf16*)(wsb + 40 * MB);   // [1536][512] = 1.5 MB
    bf16*  WoT = WqkvT + 3 * 512 * 512;      // 0.5 MB
    bf16*  W1T = WoT + 512 * 512;            // 1 MB  [1024][512]
    bf16*  W2T = W1T + 512 * 1024;           // 1 MB  [512][1024]  (ends 44 MB)
    float* KVp = (float*)(wsb + 44 * MB);    // NSLICE*32*4096*4 = 4 MB
    float* KSp = (float*)(wsb + 48 * MB);    // NSLICE*32*64*4 = 64 KB
    bf16*  F1  = (bf16*)(wsb + 0 * MB);      // 16 MB (over Qb+Kbb, free by then)
    bf16*  attnb = xn;

    float* out = (float*)d_out;
    float* y   = (float*)d_out;              // y lives in d_out (overwritten by out)
    dim3 blk(256);

    // 0. weights -> bf16 [N][K]
    wtall_kernel<<<2048, blk, 0, stream>>>(Wq, Wk, Wv, Wo, W1, W2,
                                           WqkvT, WqkvT + 512 * 512, WqkvT + 2 * 512 * 512,
                                           WoT, W1T, W2T);
    // 1. xn = LN1(x)
    ln_kernel<<<2048, blk, 0, stream>>>(x, g1, be1, xn);
    // 2. fused q/k/v projection (N=1536, GX=12)
    mfma_gemm<128, 1><<<12 * 64, blk, 0, stream>>>(
        xn, WqkvT, bq, bk, bv, nullptr, Qb, Kbb, Vb, 1536, 512, 12, 0.125f);
    // 3. KV/KS partials (no atomics, no memset)
    kv_kernel<<<dim3(32, NSLICE), blk, 0, stream>>>(Kbb, Vb, KVp, KSp);
    // 4. attn (denom + slice-reduction fused)
    attn_gemm<<<dim3(8, 64), blk, 0, stream>>>(Qb, KVp, KSp, attnb);
    // 5. y = x + attn @ Wo + bo   (into d_out)
    mfma_gemm<64, 0><<<8 * 64, blk, 0, stream>>>(
        attnb, WoT, bo, nullptr, nullptr, x, y, nullptr, nullptr, 512, 512, 8, 1.f);
    // 6. h = LN2(y)
    ln_kernel<<<2048, blk, 0, stream>>>(y, g2, be2, h);
    // 7. f1 = relu(h @ W1 + b1)
    mfma_gemm<128, 3><<<8 * 64, blk, 0, stream>>>(
        h, W1T, b1, nullptr, nullptr, nullptr, F1, nullptr, nullptr, 1024, 512, 8, 1.f);
    // 8. out = y + f1 @ W2 + b2   (reads y from d_out, writes out to d_out)
    mfma_gemm<64, 0><<<8 * 64, blk, 0, stream>>>(
        F1, W2T, b2, nullptr, nullptr, y, out, nullptr, nullptr, 512, 1024, 8, 1.f);
}

// Round 7
// 146.380 us; speedup vs baseline: 4.2796x; 1.0742x over previous
//
#include <hip/hip_runtime.h>
#include <hip/hip_bf16.h>
#include <math.h>

#define DIM 512
#define HEADS 8
#define HD 64
#define ROWS_TOTAL 8192   // 4 * 2048
#define SEQ 2048
#define NSLICE 8          // kv partial slices

typedef __hip_bfloat16 bf16;
typedef __bf16 bf16x8 __attribute__((ext_vector_type(8)));
typedef float f32x4 __attribute__((ext_vector_type(4)));

__device__ __forceinline__ float elu1(float x) {
    return x > 0.f ? x + 1.f : __expf(x);
}
__device__ __forceinline__ float b2f(unsigned short u) {
    return __uint_as_float(((unsigned int)u) << 16);
}
__device__ __forceinline__ void gl16(const void* g, void* l) {
    __builtin_amdgcn_global_load_lds(
        (const __attribute__((address_space(1))) void*)g,
        (__attribute__((address_space(3))) void*)l, 16, 0, 0);
}

// ------- LayerNorm: one wave per 512-wide row, bf16 out; input f32 or bf16
template<bool BFIN>
__global__ __launch_bounds__(256) void ln_kernel(const void* __restrict__ xv,
                                                 const float* __restrict__ g,
                                                 const float* __restrict__ b,
                                                 bf16* __restrict__ out)
{
    int row  = blockIdx.x * 4 + (threadIdx.x >> 6);
    int lane = threadIdx.x & 63;
    float f[8];
    if (BFIN) {
        const bf16* xr = (const bf16*)xv + (size_t)row * DIM + lane * 8;
        bf16x8 v = *(const bf16x8*)xr;
#pragma unroll
        for (int j = 0; j < 8; ++j) f[j] = (float)v[j];
    } else {
        const float* xr = (const float*)xv + (size_t)row * DIM + lane * 8;
        float4 v1 = *(const float4*)xr;
        float4 v2 = *(const float4*)(xr + 4);
        f[0]=v1.x; f[1]=v1.y; f[2]=v1.z; f[3]=v1.w;
        f[4]=v2.x; f[5]=v2.y; f[6]=v2.z; f[7]=v2.w;
    }
    float s = 0.f, sq = 0.f;
#pragma unroll
    for (int j = 0; j < 8; ++j) { s += f[j]; sq += f[j]*f[j]; }
#pragma unroll
    for (int off = 32; off > 0; off >>= 1) {
        s  += __shfl_xor(s,  off, 64);
        sq += __shfl_xor(sq, off, 64);
    }
    float mean = s * (1.f / DIM);
    float var  = sq * (1.f / DIM) - mean * mean;
    float rstd = rsqrtf(var + 1e-5f);
    int c = lane * 8;
    float4 ga = *(const float4*)(g + c);
    float4 gb = *(const float4*)(g + c + 4);
    float4 ba = *(const float4*)(b + c);
    float4 bb = *(const float4*)(b + c + 4);
    float gg[8] = {ga.x,ga.y,ga.z,ga.w,gb.x,gb.y,gb.z,gb.w};
    float bbv[8] = {ba.x,ba.y,ba.z,ba.w,bb.x,bb.y,bb.z,bb.w};
    bf16 ob[8];
#pragma unroll
    for (int j = 0; j < 8; ++j)
        ob[j] = __float2bfloat16((f[j] - mean) * rstd * gg[j] + bbv[j]);
    *(uint4*)(out + (size_t)row * DIM + c) = *(uint4*)ob;
}

// ---------------- transpose+convert all 6 weights: W[K][N] -> Wt[N][K] bf16
__global__ __launch_bounds__(256) void wtall_kernel(
    const float* __restrict__ Wq, const float* __restrict__ Wk,
    const float* __restrict__ Wv, const float* __restrict__ Wo,
    const float* __restrict__ W1, const float* __restrict__ W2,
    bf16* WqT, bf16* WkT, bf16* WvT, bf16* WoT, bf16* W1T, bf16* W2T)
{
    __shared__ float t[32][33];
    int bx = blockIdx.x;
    const float* W; bf16* T; int K, N, tk, tn;
    if (bx < 1024) {
        int m = bx >> 8, tix = bx & 255;
        const float* ws_[4] = {Wq, Wk, Wv, Wo};
        bf16* ts_[4] = {WqT, WkT, WvT, WoT};
        W = ws_[m]; T = ts_[m]; K = 512; N = 512; tn = tix & 15; tk = tix >> 4;
    } else if (bx < 1536) {
        int tix = bx - 1024; W = W1; T = W1T; K = 512; N = 1024; tn = tix & 31; tk = tix >> 5;
    } else {
        int tix = bx - 1536; W = W2; T = W2T; K = 1024; N = 512; tn = tix & 15; tk = tix >> 4;
    }
    int n0 = tn * 32, k0 = tk * 32;
    int tx = threadIdx.x & 31, ty = threadIdx.x >> 5;   // ty 0..7
#pragma unroll
    for (int i = 0; i < 32; i += 8)
        t[ty + i][tx] = W[(size_t)(k0 + ty + i) * N + n0 + tx];
    __syncthreads();
#pragma unroll
    for (int i = 0; i < 32; i += 8)
        T[(size_t)(n0 + ty + i) * K + k0 + tx] = __float2bfloat16(t[tx][ty + i]);
}

// ------- BMxBN bf16 MFMA GEMM, BK=64, double-buffered, XCD-swizzled -------
// 1D grid, GX = n-tiles. Wave grid 2x2: (BM/2) rows x (BN/2) cols per wave.
// EPI 0: fp32 out + bf16 resid. EPI 1: QKV-split bf16 out.
// EPI 2: bf16 out + fp32 resid. EPI 3: relu bf16 out.
template<int BM, int BN, int EPI>
__global__ __launch_bounds__(256) void mfma_gemm(
    const bf16* __restrict__ A, const bf16* __restrict__ Bt,
    const float* __restrict__ b0, const float* __restrict__ b1,
    const float* __restrict__ b2, const void* __restrict__ resid,
    void* __restrict__ O0, void* __restrict__ O1, void* __restrict__ O2,
    int N, int K, int GX, float scale)
{
    constexpr int MW = BM / 32;     // m-frags per wave
    constexpr int NW = BN / 32;     // n-frags per wave
    __shared__ __align__(16) bf16 As[2][BM * 64];
    __shared__ __align__(16) bf16 Bs[2][BN * 64];
    int tid = threadIdx.x;
    int lane = tid & 63, wid = tid >> 6;
    int wr = wid >> 1, wc = wid & 1;
    // XCD-aware swizzle (gridDim.x % 8 == 0)
    int cpx = gridDim.x >> 3;
    int work = (blockIdx.x & 7) * cpx + (blockIdx.x >> 3);
    int bx = work % GX, by = work / GX;
    int m0 = by * BM, n0 = bx * BN;
    int sr = tid >> 3;              // 0..31 staging row
    int sc = (tid & 7) * 8;         // staging col (bf16)
    const bf16* ga = A  + (size_t)(m0 + sr) * K + sc;
    const bf16* gb = Bt + (size_t)(n0 + sr) * K + sc;
    f32x4 acc[MW][NW] = {};
    int la = lane & 15, ka = lane >> 4;
    int nt = K >> 6;

    // prologue: stage tile 0 into buffer 0
#pragma unroll
    for (int j = 0; j < MW; ++j)
        gl16(ga + (size_t)j * 32 * K, &As[0][tid * 8 + j * 2048]);
#pragma unroll
    for (int j = 0; j < NW; ++j)
        gl16(gb + (size_t)j * 32 * K, &Bs[0][tid * 8 + j * 2048]);
    __syncthreads();

    for (int t = 0; t < nt; ++t) {
        int cur = t & 1;
        if (t + 1 < nt) {                       // prefetch next K-tile
            int k0 = (t + 1) << 6;
#pragma unroll
            for (int j = 0; j < MW; ++j)
                gl16(ga + (size_t)j * 32 * K + k0, &As[cur ^ 1][tid * 8 + j * 2048]);
#pragma unroll
            for (int j = 0; j < NW; ++j)
                gl16(gb + (size_t)j * 32 * K + k0, &Bs[cur ^ 1][tid * 8 + j * 2048]);
        }
        bf16x8 a[2][MW], b[2][NW];
#pragma unroll
        for (int kk = 0; kk < 2; ++kk) {
#pragma unroll
            for (int m = 0; m < MW; ++m)
                a[kk][m] = *(const bf16x8*)&As[cur][(wr * (BM/2) + m * 16 + la) * 64 + kk * 32 + ka * 8];
#pragma unroll
            for (int n = 0; n < NW; ++n)
                b[kk][n] = *(const bf16x8*)&Bs[cur][(wc * (BN/2) + n * 16 + la) * 64 + kk * 32 + ka * 8];
        }
#pragma unroll
        for (int kk = 0; kk < 2; ++kk)
#pragma unroll
            for (int m = 0; m < MW; ++m)
#pragma unroll
                for (int n = 0; n < NW; ++n)
                    acc[m][n] = __builtin_amdgcn_mfma_f32_16x16x32_bf16(a[kk][m], b[kk][n], acc[m][n], 0, 0, 0);
        __syncthreads();   // drains prefetch (vmcnt) + protects buffers
    }

    int rg = (lane >> 4) * 4;
    if (EPI == 1) {
        // QKV split over bx blocks of 8 (N=1536, BN=64): q | k | v
        int bsel = bx >> 3;
        bf16* Ob = (bf16*)(bsel == 0 ? O0 : (bsel == 1 ? O1 : O2));
        const float* bb = bsel == 0 ? b0 : (bsel == 1 ? b1 : b2);
        int nloc0 = (bx & 7) * BN;
#pragma unroll
        for (int m = 0; m < MW; ++m) {
            int gm = m0 + wr * (BM/2) + m * 16 + rg;
#pragma unroll
            for (int n = 0; n < NW; ++n) {
                int gnl = nloc0 + wc * (BN/2) + n * 16 + la;
                float bv_ = bb[gnl];
#pragma unroll
                for (int j = 0; j < 4; ++j) {
                    float v = acc[m][n][j] + bv_;
                    if (bsel == 0)      v = elu1(v * scale);
                    else if (bsel == 1) v = elu1(v);
                    Ob[(size_t)(gm + j) * 512 + gnl] = __float2bfloat16(v);
                }
            }
        }
    } else {
#pragma unroll
        for (int m = 0; m < MW; ++m) {
            int gm = m0 + wr * (BM/2) + m * 16 + rg;
#pragma unroll
            for (int n = 0; n < NW; ++n) {
                int gn = n0 + wc * (BN/2) + n * 16 + la;
                float bv_ = b0[gn];
#pragma unroll
                for (int j = 0; j < 4; ++j) {
                    float v = acc[m][n][j] + bv_;
                    if (EPI == 3) v = fmaxf(v, 0.f);
                    if (EPI == 0 && resid)
                        v += (float)((const bf16*)resid)[(size_t)(gm + j) * N + gn];
                    if (EPI == 2 && resid)
                        v += ((const float*)resid)[(size_t)(gm + j) * N + gn];
                    if (EPI == 0) ((float*)O0)[(size_t)(gm + j) * N + gn] = v;
                    else          ((bf16*)O0)[(size_t)(gm + j) * N + gn] = __float2bfloat16(v);
                }
            }
        }
    }
}

// ---- per-head KV partials: KVp[slice][bh][d][e], KSp[slice][bh][e] -------
__global__ __launch_bounds__(256) void kv_kernel(
    const bf16* __restrict__ k, const bf16* __restrict__ v,
    float* __restrict__ KVp, float* __restrict__ KSp)
{
    __shared__ float Ks[16][68];
    __shared__ float Vs[16][68];
    int bh = blockIdx.x;           // 0..31  (= b*8 + h)
    int sl = blockIdx.y;           // 0..NSLICE-1
    int b = bh >> 3, h = bh & 7;
    int tid = threadIdx.x;
    int rbase = b * SEQ + sl * (SEQ / NSLICE);
    int lr = tid >> 4;
    int lc = (tid & 15) * 4;
    int e  = tid & 63;
    int d0 = (tid >> 6) * 16;
    float acc[16] = {};
    float ks_acc = 0.f;
    for (int c = 0; c < SEQ / NSLICE; c += 16) {
        const ushort4 k4 = *(const ushort4*)(k + (size_t)(rbase + c + lr) * DIM + h * HD + lc);
        Ks[lr][lc + 0] = b2f(k4.x); Ks[lr][lc + 1] = b2f(k4.y);
        Ks[lr][lc + 2] = b2f(k4.z); Ks[lr][lc + 3] = b2f(k4.w);
        const ushort4 v4 = *(const ushort4*)(v + (size_t)(rbase + c + lr) * DIM + h * HD + lc);
        Vs[lr][lc + 0] = b2f(v4.x); Vs[lr][lc + 1] = b2f(v4.y);
        Vs[lr][lc + 2] = b2f(v4.z); Vs[lr][lc + 3] = b2f(v4.w);
        __syncthreads();
#pragma unroll
        for (int nn = 0; nn < 16; ++nn) {
            float vv = Vs[nn][e];
#pragma unroll
            for (int i = 0; i < 16; ++i)
                acc[i] += Ks[nn][d0 + i] * vv;
            if (d0 == 0) ks_acc += Ks[nn][e];
        }
        __syncthreads();
    }
    float* kvp = KVp + ((size_t)sl * 32 + bh) * (HD * HD);
#pragma unroll
    for (int i = 0; i < 16; ++i)
        kvp[(d0 + i) * HD + e] = acc[i];   // kv[d][e]
    if (d0 == 0) KSp[((size_t)sl * 32 + bh) * HD + e] = ks_acc;
}

// ---- attn: out[128 rows, head] = (Q_h @ KV_h^T) / (Q_h . ksum_h + 1e-5) --
// KV/KS reduced over NSLICE partials during the LDS load.
__global__ __launch_bounds__(256) void attn_gemm(
    const bf16* __restrict__ Q, const float* __restrict__ KVp,
    const float* __restrict__ KSp, bf16* __restrict__ out)
{
    __shared__ __align__(16) bf16 As[128][72];
    __shared__ __align__(16) bf16 Bs[64][72];
    __shared__ float ks[64];
    __shared__ float dn[128];
    int h = blockIdx.x;
    int m0 = blockIdx.y * 128;
    int bh = ((m0 >> 11) << 3) + h;
    int tid = threadIdx.x;
    int lane = tid & 63, wid = tid >> 6;
    {
        int r = tid >> 3, c0 = (tid & 7) * 8;
#pragma unroll
        for (int p = 0; p < 4; ++p) {
            int row = p * 32 + r;
            *(bf16x8*)&As[row][c0] =
                *(const bf16x8*)(Q + (size_t)(m0 + row) * DIM + h * HD + c0);
        }
        const float* kvb = KVp + (size_t)bh * (HD * HD);
        int e = tid & 63, d0 = (tid >> 6) * 16;
        float s_[16] = {};
#pragma unroll
        for (int sl = 0; sl < NSLICE; ++sl)
#pragma unroll
            for (int i = 0; i < 16; ++i)
                s_[i] += kvb[(size_t)sl * 32 * (HD * HD) + (d0 + i) * HD + e];
#pragma unroll
        for (int i = 0; i < 16; ++i)
            Bs[e][d0 + i] = __float2bfloat16(s_[i]);   // Bs[e][d]=KV[d][e]
        if (tid < 64) {
            float s = 0.f;
#pragma unroll
            for (int sl = 0; sl < NSLICE; ++sl)
                s += KSp[((size_t)sl * 32 + bh) * HD + tid];
            ks[tid] = s;
        }
    }
    __syncthreads();
    // denom: 128 threads, one row each: q_h[row] . ksum_h
    if (tid < 128) {
        float s = 0.f;
#pragma unroll
        for (int c = 0; c < 8; ++c) {
            bf16x8 qv = *(const bf16x8*)&As[tid][c * 8];
#pragma unroll
            for (int j = 0; j < 8; ++j)
                s += (float)qv[j] * ks[c * 8 + j];
        }
        dn[tid] = 1.f / (s + 1e-5f);
    }
    int la = lane & 15, ka = lane >> 4;
    f32x4 acc[2][4] = {};
#pragma unroll
    for (int s = 0; s < 2; ++s) {
        bf16x8 a[2], b[4];
#pragma unroll
        for (int m = 0; m < 2; ++m)
            a[m] = *(const bf16x8*)&As[wid * 32 + m * 16 + la][s * 32 + ka * 8];
#pragma unroll
        for (int n = 0; n < 4; ++n)
            b[n] = *(const bf16x8*)&Bs[n * 16 + la][s * 32 + ka * 8];
#pragma unroll
        for (int m = 0; m < 2; ++m)
#pragma unroll
            for (int n = 0; n < 4; ++n)
                acc[m][n] = __builtin_amdgcn_mfma_f32_16x16x32_bf16(a[m], b[n], acc[m][n], 0, 0, 0);
    }
    __syncthreads();   // dn visible
    int rg = (lane >> 4) * 4;
#pragma unroll
    for (int m = 0; m < 2; ++m) {
#pragma unroll
        for (int j = 0; j < 4; ++j) {
            int lr = wid * 32 + m * 16 + rg + j;
            float rdn = dn[lr];
            int gm = m0 + lr;
#pragma unroll
            for (int n = 0; n < 4; ++n) {
                int gn = h * HD + n * 16 + la;
                out[(size_t)gm * DIM + gn] = __float2bfloat16(acc[m][n][j] * rdn);
            }
        }
    }
}

extern "C" void kernel_launch(void* const* d_in, const int* in_sizes, int n_in,
                              void* d_out, int out_size, void* d_ws, size_t ws_size,
                              hipStream_t stream)
{
    const float* x   = (const float*)d_in[0];
    const float* Wq  = (const float*)d_in[1];
    const float* bq  = (const float*)d_in[2];
    const float* Wk  = (const float*)d_in[3];
    const float* bk  = (const float*)d_in[4];
    const float* Wv  = (const float*)d_in[5];
    const float* bv  = (const float*)d_in[6];
    const float* Wo  = (const float*)d_in[7];
    const float* bo  = (const float*)d_in[8];
    const float* W1  = (const float*)d_in[9];
    const float* b1  = (const float*)d_in[10];
    const float* W2  = (const float*)d_in[11];
    const float* b2  = (const float*)d_in[12];
    const float* g1  = (const float*)d_in[13];
    const float* be1 = (const float*)d_in[14];
    const float* g2  = (const float*)d_in[15];
    const float* be2 = (const float*)d_in[16];

    char* wsb = (char*)d_ws;
    const size_t MB = 1u << 20;
    bf16*  Qb  = (bf16*)(wsb + 0 * MB);      // 8 MB
    bf16*  Kbb = (bf16*)(wsb + 8 * MB);      // 8 MB
    bf16*  Vb  = (bf16*)(wsb + 16 * MB);     // 8 MB
    bf16*  xn  = (bf16*)(wsb + 24 * MB);     // 8 MB; attnb reuses after QKV
    bf16*  yb  = (bf16*)(wsb + 32 * MB);     // 8 MB  (y residual, bf16)
    bf16*  h   = (bf16*)(wsb + 40 * MB);     // 8 MB
    bf16*  WqkvT = (bf16*)(wsb + 48 * MB);   // [1536][512] = 1.5 MB
    bf16*  WoT = WqkvT + 3 * 512 * 512;      // 0.5 MB
    bf16*  W1T = WoT + 512 * 512;            // 1 MB  [1024][512]
    bf16*  W2T = W1T + 512 * 1024;           // 1 MB  [512][1024]  (ends 52.5)
    float* KVp = (float*)(wsb + 53 * MB);    // NSLICE*32*4096*4 = 4 MB
    float* KSp = (float*)(wsb + 57 * MB);    // 64 KB
    bf16*  F1  = (bf16*)(wsb + 0 * MB);      // 16 MB (over Qb+Kbb, free by then)
    bf16*  attnb = xn;

    float* out = (float*)d_out;
    dim3 blk(256);

    // 0. weights -> bf16 [N][K]
    wtall_kernel<<<2048, blk, 0, stream>>>(Wq, Wk, Wv, Wo, W1, W2,
                                           WqkvT, WqkvT + 512 * 512, WqkvT + 2 * 512 * 512,
                                           WoT, W1T, W2T);
    // 1. xn = LN1(x)
    ln_kernel<false><<<2048, blk, 0, stream>>>(x, g1, be1, xn);
    // 2. fused q/k/v projection (N=1536, BM=128 BN=64, GX=24, 1536 blocks)
    mfma_gemm<128, 64, 1><<<1536, blk, 0, stream>>>(
        xn, WqkvT, bq, bk, bv, nullptr, Qb, Kbb, Vb, 1536, 512, 24, 0.125f);
    // 3. KV/KS partials (no atomics, no memset)
    kv_kernel<<<dim3(32, NSLICE), blk, 0, stream>>>(Kbb, Vb, KVp, KSp);
    // 4. attn (denom + slice-reduction fused)
    attn_gemm<<<dim3(8, 64), blk, 0, stream>>>(Qb, KVp, KSp, attnb);
    // 5. y = x + attn @ Wo + bo   (bf16 out, fp32 resid; 64x64, 1024 blocks)
    mfma_gemm<64, 64, 2><<<1024, blk, 0, stream>>>(
        attnb, WoT, bo, nullptr, nullptr, x, yb, nullptr, nullptr, 512, 512, 8, 1.f);
    // 6. h = LN2(yb)
    ln_kernel<true><<<2048, blk, 0, stream>>>(yb, g2, be2, h);
    // 7. f1 = relu(h @ W1 + b1)  (64x64, 2048 blocks)
    mfma_gemm<64, 64, 3><<<2048, blk, 0, stream>>>(
        h, W1T, b1, nullptr, nullptr, nullptr, F1, nullptr, nullptr, 1024, 512, 16, 1.f);
    // 8. out = yb + f1 @ W2 + b2  (fp32 out, bf16 resid; 64x64, 1024 blocks)
    mfma_gemm<64, 64, 0><<<1024, blk, 0, stream>>>(
        F1, W2T, b2, nullptr, nullptr, yb, out, nullptr, nullptr, 512, 1024, 8, 1.f);
}